// Round 5
// baseline (105.829 us; speedup 1.0000x reference)
//
#include <hip/hip_runtime.h>

// Rattle B=64, C=64, N=4096 (K = 12288). out = [mom_out (B*N*3), lmd (B*C)] fp32.
//
// J = -dtm * (W.jac) jac^T  (neg-definite Gram), c0 = (W.jac).mom
// lmd = -J^{-1} c0 = G^{-1} c0 / dtm  with G = (W.jac) jac^T  (SPD, cond ~1.3)
// mom_out = mom - dtm * jac^T lmd
//
// K1: bf16-MFMA partial Grams (fp32 c0 path) + fp8-e4m3 jac copy for K3.
//     QB=16 chunks -> 1024 blocks = 4 blocks/CU (inter-block overlap hides
//     the staging barriers; R3 showed intra-block pipelining doesn't).
//     jac/mom loads are nontemporal: single-use stream, keeps jac8 in L3.
// K2: Jacobi-Richardson solve (rho ~0.16 -> 8 iters; 1 barrier/iter),
//     1024 threads for parallel 16-partial reduction.
// K3: rank-64 momentum update reading the 50 MB fp8 copy (L3-resident)

namespace {
constexpr int Bb = 64;
constexpr int Cc = 64;
constexpr int Kk = 12288;
constexpr int QB = 16;            // K-chunks per replica
constexpr int KCHUNK = Kk / QB;   // 768
constexpr int NT = KCHUNK / 64;   // 12 tiles of 64 k-floats
constexpr size_t J8_BYTES = (size_t)Bb * Cc * Kk;          // 50,331,648
constexpr size_t GPART_FLOATS = (size_t)Bb * QB * 4096;    // 4,194,304
constexpr size_t C0_FLOATS = (size_t)Bb * QB * 64;         // 65,536
constexpr size_t WS_NEED = J8_BYTES + (GPART_FLOATS + C0_FLOATS) * 4;
}

typedef __attribute__((ext_vector_type(8))) __bf16 bf16x8;
typedef __attribute__((ext_vector_type(16))) float f32x16;
typedef __attribute__((ext_vector_type(4))) float f32x4;   // clang-native: ok for nontemporal builtins
typedef __attribute__((ext_vector_type(2))) float f32x2;
typedef __attribute__((ext_vector_type(4))) unsigned int u32x4;

// ---------------- K1: partial Gram via MFMA + fp32 c0 (+ fp8 jac copy) ----
// grid 1024 = (b, qb); 256 threads (4 waves). Each block: 64x64 Gram partial
// over a 768-wide K chunk. LDS bf16 tiles [64 rows][64 k], XOR-swizzled
// (elem ^= (row&7)<<3) so 32-row b128 fragment reads are conflict-free.
template <bool WRITE8>
__global__ __launch_bounds__(256, 4) void k1_gram(const float* __restrict__ jac,
                                                  const float* __restrict__ mas,
                                                  const float* __restrict__ mom,
                                                  float* __restrict__ Gpart,
                                                  float* __restrict__ c0part,
                                                  unsigned char* __restrict__ jac8) {
    __shared__ __align__(16) __bf16 AhL[64 * 64];   // bf16(w * jac)
    __shared__ __align__(16) __bf16 BhL[64 * 64];   // bf16(jac)
    __shared__ __align__(16) float wLds[KCHUNK];
    __shared__ float c0red[4][64];

    const int b   = blockIdx.x >> 4;
    const int qb  = blockIdx.x & 15;
    const int tid = threadIdx.x;
    const int kbeg = qb * KCHUNK;

    // per-chunk weights w = 1/mas (fp32, exact-path for c0)
    for (int kk = tid; kk < KCHUNK; kk += 256)
        wLds[kk] = 1.0f / mas[b * 4096 + (kbeg + kk) / 3];

    // staging map: row cS (0..63), 16-k segment gS (0..3)
    const int cS = tid >> 2, gS = tid & 3;
    const float* jrow = jac + (size_t)(b * 64 + cS) * Kk;
    const float* momB = mom + (size_t)b * Kk;
    unsigned char* j8row = jac8 + (size_t)(b * 64 + cS) * Kk;  // byte/elem
    const int swzS = (cS & 7) << 3;

    // MFMA map: wave w -> 32x32 tile (i0, j0); lane r = row-in-tile, kg = k-half
    const int w = tid >> 6, lane = tid & 63;
    const int i0 = (w & 1) << 5, j0 = (w >> 1) << 5;
    const int r = lane & 31, kg = lane >> 5;
    const int arow = i0 + r, brow = j0 + r;
    const int abase = arow * 64, aswz = (arow & 7) << 3;
    const int bbase = brow * 64, bswz = (brow & 7) << 3;

    f32x16 acc;
#pragma unroll
    for (int z = 0; z < 16; ++z) acc[z] = 0.0f;
    float c0acc = 0.0f;

    __syncthreads();  // wLds ready

    for (int t = 0; t < NT; ++t) {
        const int k0 = kbeg + t * 64;
        const f32x4* jp = (const f32x4*)(jrow + k0 + gS * 16);
        const f32x4* wp = (const f32x4*)(wLds + (k0 - kbeg) + gS * 16);
        const f32x4* mp = (const f32x4*)(momB + k0 + gS * 16);

        bf16x8 ah[2], bh[2];
        int pk[4];
#pragma unroll
        for (int v = 0; v < 4; ++v) {
            f32x4 x = __builtin_nontemporal_load(&jp[v]);  // single-use stream
            f32x4 wv = wp[v];
            f32x4 m = __builtin_nontemporal_load(&mp[v]);
            float y0 = x.x * wv.x, y1 = x.y * wv.y, y2 = x.z * wv.z, y3 = x.w * wv.w;
            c0acc += y0 * m.x + y1 * m.y + y2 * m.z + y3 * m.w;
            const int h = v >> 1, e0 = (v & 1) * 4;
            ah[h][e0 + 0] = (__bf16)y0; ah[h][e0 + 1] = (__bf16)y1;
            ah[h][e0 + 2] = (__bf16)y2; ah[h][e0 + 3] = (__bf16)y3;
            bh[h][e0 + 0] = (__bf16)x.x; bh[h][e0 + 1] = (__bf16)x.y;
            bh[h][e0 + 2] = (__bf16)x.z; bh[h][e0 + 3] = (__bf16)x.w;
            if (WRITE8) {
                int lo = __builtin_amdgcn_cvt_pk_fp8_f32(x.x, x.y, 0, false);
                pk[v]  = __builtin_amdgcn_cvt_pk_fp8_f32(x.z, x.w, lo, true);
            }
        }
        if (WRITE8) {
            u32x4 u = {(unsigned)pk[0], (unsigned)pk[1], (unsigned)pk[2], (unsigned)pk[3]};
            *(u32x4*)(j8row + k0 + gS * 16) = u;   // cached: K3 wants L3 hits
        }
#pragma unroll
        for (int h = 0; h < 2; ++h) {
            const int off = cS * 64 + ((gS * 16 + h * 8) ^ swzS);
            *(bf16x8*)&AhL[off] = ah[h];
            *(bf16x8*)&BhL[off] = bh[h];
        }
        __syncthreads();

#pragma unroll
        for (int ks = 0; ks < 4; ++ks) {
            const int kc = ks * 16 + kg * 8;
            bf16x8 a  = *(const bf16x8*)&AhL[abase + (kc ^ aswz)];
            bf16x8 bb = *(const bf16x8*)&BhL[bbase + (kc ^ bswz)];
            acc = __builtin_amdgcn_mfma_f32_32x32x16_bf16(a, bb, acc, 0, 0, 0);
        }
        __syncthreads();
    }

    // C/D layout (m74/m101): col = lane&31, row = (reg&3) + 8*(reg>>2) + 4*(lane>>5)
    float* Gp = Gpart + (size_t)(b * QB + qb) * 4096;
#pragma unroll
    for (int reg = 0; reg < 16; ++reg) {
        const int row = (reg & 3) + 8 * (reg >> 2) + 4 * kg;
        Gp[(i0 + row) * 64 + (j0 + r)] = acc[reg];
    }

    c0red[gS][cS] = c0acc;
    __syncthreads();
    if (tid < 64)
        c0part[(b * QB + qb) * 64 + tid] =
            c0red[0][tid] + c0red[1][tid] + c0red[2][tid] + c0red[3][tid];
}

// ---------------- K2: Jacobi-Richardson solve  G z = c0, lmd = z/dtm ------
// One block (1024 thr = 16 waves) per replica. G = sum of 16 partials (SPD,
// diag-dominant: iteration matrix I - D^-1 G has spectral radius ~0.16,
// so 8 iterations leave ~7e-8 relative error, far below bf16-Gram noise).
// One barrier/iter: parity-buffered partials + wave-private z copy.
__global__ __launch_bounds__(1024) void k2_solve(const float* __restrict__ Gpart,
                                                 const float* __restrict__ c0part,
                                                 const float* __restrict__ dtm,
                                                 float* __restrict__ lmd_out) {
    __shared__ __align__(16) float G[64][68];
    __shared__ float red[2][16][64];
    __shared__ float zw[16][64];

    const int b = blockIdx.x;
    const int t = threadIdx.x;
    const int i = t & 63, q = t >> 6;   // q: wave 0..15

    // reduce the 16 Gram partials (one float4 per thread, 16 loads in flight)
    {
        float4 s = {0.0f, 0.0f, 0.0f, 0.0f};
#pragma unroll
        for (int qq = 0; qq < QB; ++qq) {
            float4 v = *(const float4*)&Gpart[(size_t)(b * QB + qq) * 4096 + t * 4];
            s.x += v.x; s.y += v.y; s.z += v.z; s.w += v.w;
        }
        *(float4*)&G[t >> 4][(t & 15) * 4] = s;
    }
    // c0[i]: every thread (q,i) computes it (waves redundant, identical fp)
    float c0 = 0.0f;
#pragma unroll
    for (int qq = 0; qq < QB; ++qq) c0 += c0part[(b * QB + qq) * 64 + i];
    __syncthreads();  // G ready

    const float invD = 1.0f / G[i][i];
    float z = c0 * invD;          // z0 = D^-1 c0
    zw[q][i] = z;                 // wave-private copy (same-wave read only)

    for (int it = 0; it < 8; ++it) {
        // partial dot: s = G[i][4q:4q+4] . z[4q:4q+4]
        float4 g4 = *(const float4*)&G[i][q * 4];
        float4 z4 = *(const float4*)&zw[q][q * 4];   // own wave's writes
        float s = g4.x * z4.x + g4.y * z4.y + g4.z * z4.z + g4.w * z4.w;
        const int p = it & 1;
        red[p][q][i] = s;
        __syncthreads();  // red[p] complete
        float rres = c0;
#pragma unroll
        for (int qq = 0; qq < 16; ++qq) rres -= red[p][qq][i];
        z += rres * invD;         // identical in all 16 waves
        zw[q][i] = z;             // refresh own wave's copy (in-order DS)
    }

    if (t < 64) lmd_out[b * 64 + t] = z * (1.0f / dtm[b]);
}

// ---------------- K3 (fp8): mom_out = mom - dtm * jac8^T lmd --------------
// grid (6, 64), 256 thr. Each thread: 8 k-values; 64 rows x 8B fp8 loads
// (the 50 MB fp8 buffer was written by K1 just before -> L3-resident).
__global__ __launch_bounds__(256) void k3_momout_fp8(const unsigned char* __restrict__ jac8,
                                                     const float* __restrict__ mom,
                                                     const float* __restrict__ dtm,
                                                     const float* __restrict__ lmd,
                                                     float* __restrict__ mom_out) {
    __shared__ float lLds[64];
    const int b   = blockIdx.y;
    const int blk = blockIdx.x;
    const int t   = threadIdx.x;
    if (t < 64) lLds[t] = lmd[b * 64 + t];
    __syncthreads();

    const int kbase = blk * 2048 + t * 8;
    const unsigned char* jp = jac8 + (size_t)b * Cc * Kk + kbase;

    float acc[8];
#pragma unroll
    for (int z = 0; z < 8; ++z) acc[z] = 0.0f;

#pragma unroll 8
    for (int c = 0; c < 64; ++c) {
        uint2 u = *(const uint2*)(jp + (size_t)c * Kk);
        const float lc = lLds[c];
        f32x2 d;
        d = __builtin_amdgcn_cvt_pk_f32_fp8(u.x, false); acc[0] += lc * d[0]; acc[1] += lc * d[1];
        d = __builtin_amdgcn_cvt_pk_f32_fp8(u.x, true);  acc[2] += lc * d[0]; acc[3] += lc * d[1];
        d = __builtin_amdgcn_cvt_pk_f32_fp8(u.y, false); acc[4] += lc * d[0]; acc[5] += lc * d[1];
        d = __builtin_amdgcn_cvt_pk_f32_fp8(u.y, true);  acc[6] += lc * d[0]; acc[7] += lc * d[1];
    }
    const float dt = dtm[b];
    const float* mb = mom + (size_t)b * Kk + kbase;
    float4 m0 = *(const float4*)mb;
    float4 m1 = *(const float4*)(mb + 4);
    f32x4 o0, o1;
    o0.x = m0.x - dt * acc[0]; o0.y = m0.y - dt * acc[1];
    o0.z = m0.z - dt * acc[2]; o0.w = m0.w - dt * acc[3];
    o1.x = m1.x - dt * acc[4]; o1.y = m1.y - dt * acc[5];
    o1.z = m1.z - dt * acc[6]; o1.w = m1.w - dt * acc[7];
    float* ob = mom_out + (size_t)b * Kk + kbase;
    __builtin_nontemporal_store(o0, (f32x4*)ob);
    __builtin_nontemporal_store(o1, (f32x4*)(ob + 4));
}

// ---------------- K3 (fp32 fallback, ws too small) ------------------------
__global__ __launch_bounds__(256) void k3_momout(const float* __restrict__ jac,
                                                 const float* __restrict__ mom,
                                                 const float* __restrict__ dtm,
                                                 const float* __restrict__ lmd,
                                                 float* __restrict__ mom_out) {
    __shared__ float lLds[64];
    const int b   = blockIdx.y;
    const int blk = blockIdx.x;
    const int t   = threadIdx.x;
    if (t < 64) lLds[t] = lmd[b * 64 + t];
    __syncthreads();

    const size_t kbase = (size_t)blk * 1024 + (size_t)t * 4;
    const float* jp = jac + (size_t)b * Cc * Kk + kbase;

    float4 acc = {0.0f, 0.0f, 0.0f, 0.0f};
#pragma unroll 4
    for (int c = 0; c < 64; ++c) {
        float4 jv = *(const float4*)(jp + (size_t)c * Kk);
        float lc = lLds[c];
        acc.x += lc * jv.x;
        acc.y += lc * jv.y;
        acc.z += lc * jv.z;
        acc.w += lc * jv.w;
    }
    const float dt = dtm[b];
    float4 m4 = *(const float4*)(mom + (size_t)b * Kk + kbase);
    float4 o;
    o.x = m4.x - dt * acc.x;
    o.y = m4.y - dt * acc.y;
    o.z = m4.z - dt * acc.z;
    o.w = m4.w - dt * acc.w;
    *(float4*)(mom_out + (size_t)b * Kk + kbase) = o;
}

extern "C" void kernel_launch(void* const* d_in, const int* in_sizes, int n_in,
                              void* d_out, int out_size, void* d_ws, size_t ws_size,
                              hipStream_t stream) {
    const float* mom = (const float*)d_in[0];
    const float* mas = (const float*)d_in[1];
    const float* dtm = (const float*)d_in[2];
    const float* jac = (const float*)d_in[3];

    float* out = (float*)d_out;            // mom_out: Bb*Kk
    float* lmd = out + (size_t)Bb * Kk;    // lmd: Bb*Cc

    const bool use_fp8 = ws_size >= WS_NEED;

    unsigned char* jac8 = (unsigned char*)d_ws;          // Bb*Cc*Kk bytes
    float* Gpart;
    float* c0part;
    if (use_fp8) {
        Gpart = (float*)(jac8 + J8_BYTES);
        c0part = Gpart + GPART_FLOATS;
    } else {
        Gpart = (float*)d_ws;
        c0part = Gpart + GPART_FLOATS;
    }

    if (use_fp8) {
        k1_gram<true><<<Bb * QB, 256, 0, stream>>>(jac, mas, mom, Gpart, c0part, jac8);
        k2_solve<<<Bb, 1024, 0, stream>>>(Gpart, c0part, dtm, lmd);
        k3_momout_fp8<<<dim3(6, 64), 256, 0, stream>>>(jac8, mom, dtm, lmd, out);
    } else {
        k1_gram<false><<<Bb * QB, 256, 0, stream>>>(jac, mas, mom, Gpart, c0part, nullptr);
        k2_solve<<<Bb, 1024, 0, stream>>>(Gpart, c0part, dtm, lmd);
        k3_momout<<<dim3(12, 64), 256, 0, stream>>>(jac, mom, dtm, lmd, out);
    }
}

// Round 6
// 73.186 us; speedup vs baseline: 1.4460x; 1.4460x over previous
//
#include <hip/hip_runtime.h>

// Rattle B=64, C=64, N=4096 (K = 12288). out = [mom_out (B*N*3), lmd (B*C)] fp32.
//
// J = -dtm * (W.jac) jac^T  (neg-definite Gram), c0 = (W.jac).mom
// lmd = -J^{-1} c0 = G^{-1} c0 / dtm  with G = (W.jac) jac^T  (SPD, cond ~1.3)
// mom_out = mom - dtm * jac^T lmd
//
// K1: bf16-MFMA partial Grams (fp32 c0 path) + fp8-e4m3 jac copy for K3.
//     QB=16 chunks -> 1024 blocks = up to 4 blocks/CU for inter-block
//     overlap. PLAIN launch_bounds (R5 lesson: forcing 4 blocks/CU via
//     __launch_bounds__(256,4) capped VGPRs at 128 -> spills -> +39us).
//     No nontemporal hints (they bypass L2/L3 on re-used lines).
// K2: Jacobi-Richardson solve (rho ~0.16 -> 8 iters; 1 barrier/iter)
// K3: rank-64 momentum update reading the 50 MB fp8 copy (L3-resident)

namespace {
constexpr int Bb = 64;
constexpr int Cc = 64;
constexpr int Kk = 12288;
constexpr int QB = 16;            // K-chunks per replica
constexpr int KCHUNK = Kk / QB;   // 768
constexpr int NT = KCHUNK / 64;   // 12 tiles of 64 k-floats
constexpr size_t J8_BYTES = (size_t)Bb * Cc * Kk;          // 50,331,648
constexpr size_t GPART_FLOATS = (size_t)Bb * QB * 4096;    // 4,194,304
constexpr size_t C0_FLOATS = (size_t)Bb * QB * 64;         // 65,536
constexpr size_t WS_NEED = J8_BYTES + (GPART_FLOATS + C0_FLOATS) * 4;
}

typedef __attribute__((ext_vector_type(8))) __bf16 bf16x8;
typedef __attribute__((ext_vector_type(16))) float f32x16;
typedef __attribute__((ext_vector_type(2))) float f32x2;

// ---------------- K1: partial Gram via MFMA + fp32 c0 (+ fp8 jac copy) ----
// grid 1024 = (b, qb); 256 threads (4 waves). Each block: 64x64 Gram partial
// over a 768-wide K chunk. LDS bf16 tiles [64 rows][64 k], XOR-swizzled
// (elem ^= (row&7)<<3) so 32-row b128 fragment reads are conflict-free.
template <bool WRITE8>
__global__ __launch_bounds__(256) void k1_gram(const float* __restrict__ jac,
                                               const float* __restrict__ mas,
                                               const float* __restrict__ mom,
                                               float* __restrict__ Gpart,
                                               float* __restrict__ c0part,
                                               unsigned char* __restrict__ jac8) {
    __shared__ __align__(16) __bf16 AhL[64 * 64];   // bf16(w * jac)
    __shared__ __align__(16) __bf16 BhL[64 * 64];   // bf16(jac)
    __shared__ __align__(16) float wLds[KCHUNK];
    __shared__ float c0red[4][64];

    const int b   = blockIdx.x >> 4;
    const int qb  = blockIdx.x & 15;
    const int tid = threadIdx.x;
    const int kbeg = qb * KCHUNK;

    // per-chunk weights w = 1/mas (fp32, exact-path for c0)
    for (int kk = tid; kk < KCHUNK; kk += 256)
        wLds[kk] = 1.0f / mas[b * 4096 + (kbeg + kk) / 3];

    // staging map: row cS (0..63), 16-k segment gS (0..3)
    const int cS = tid >> 2, gS = tid & 3;
    const float* jrow = jac + (size_t)(b * 64 + cS) * Kk;
    const float* momB = mom + (size_t)b * Kk;
    unsigned char* j8row = jac8 + (size_t)(b * 64 + cS) * Kk;  // byte/elem
    const int swzS = (cS & 7) << 3;

    // MFMA map: wave w -> 32x32 tile (i0, j0); lane r = row-in-tile, kg = k-half
    const int w = tid >> 6, lane = tid & 63;
    const int i0 = (w & 1) << 5, j0 = (w >> 1) << 5;
    const int r = lane & 31, kg = lane >> 5;
    const int arow = i0 + r, brow = j0 + r;
    const int abase = arow * 64, aswz = (arow & 7) << 3;
    const int bbase = brow * 64, bswz = (brow & 7) << 3;

    f32x16 acc;
#pragma unroll
    for (int z = 0; z < 16; ++z) acc[z] = 0.0f;
    float c0acc = 0.0f;

    __syncthreads();  // wLds ready

    for (int t = 0; t < NT; ++t) {
        const int k0 = kbeg + t * 64;
        const float4* jp = (const float4*)(jrow + k0 + gS * 16);
        const float4* wp = (const float4*)(wLds + (k0 - kbeg) + gS * 16);
        const float4* mp = (const float4*)(momB + k0 + gS * 16);

        bf16x8 ah[2], bh[2];
        int pk[4];
#pragma unroll
        for (int v = 0; v < 4; ++v) {
            float4 x = jp[v];
            float4 wv = wp[v];
            float4 m = mp[v];
            float y0 = x.x * wv.x, y1 = x.y * wv.y, y2 = x.z * wv.z, y3 = x.w * wv.w;
            c0acc += y0 * m.x + y1 * m.y + y2 * m.z + y3 * m.w;
            const int h = v >> 1, e0 = (v & 1) * 4;
            ah[h][e0 + 0] = (__bf16)y0; ah[h][e0 + 1] = (__bf16)y1;
            ah[h][e0 + 2] = (__bf16)y2; ah[h][e0 + 3] = (__bf16)y3;
            bh[h][e0 + 0] = (__bf16)x.x; bh[h][e0 + 1] = (__bf16)x.y;
            bh[h][e0 + 2] = (__bf16)x.z; bh[h][e0 + 3] = (__bf16)x.w;
            if (WRITE8) {
                int lo = __builtin_amdgcn_cvt_pk_fp8_f32(x.x, x.y, 0, false);
                pk[v]  = __builtin_amdgcn_cvt_pk_fp8_f32(x.z, x.w, lo, true);
            }
        }
        if (WRITE8) {
            uint4 u = {(unsigned)pk[0], (unsigned)pk[1], (unsigned)pk[2], (unsigned)pk[3]};
            *(uint4*)(j8row + k0 + gS * 16) = u;
        }
#pragma unroll
        for (int h = 0; h < 2; ++h) {
            const int off = cS * 64 + ((gS * 16 + h * 8) ^ swzS);
            *(bf16x8*)&AhL[off] = ah[h];
            *(bf16x8*)&BhL[off] = bh[h];
        }
        __syncthreads();

#pragma unroll
        for (int ks = 0; ks < 4; ++ks) {
            const int kc = ks * 16 + kg * 8;
            bf16x8 a  = *(const bf16x8*)&AhL[abase + (kc ^ aswz)];
            bf16x8 bb = *(const bf16x8*)&BhL[bbase + (kc ^ bswz)];
            acc = __builtin_amdgcn_mfma_f32_32x32x16_bf16(a, bb, acc, 0, 0, 0);
        }
        __syncthreads();
    }

    // C/D layout (m74/m101): col = lane&31, row = (reg&3) + 8*(reg>>2) + 4*(lane>>5)
    float* Gp = Gpart + (size_t)(b * QB + qb) * 4096;
#pragma unroll
    for (int reg = 0; reg < 16; ++reg) {
        const int row = (reg & 3) + 8 * (reg >> 2) + 4 * kg;
        Gp[(i0 + row) * 64 + (j0 + r)] = acc[reg];
    }

    c0red[gS][cS] = c0acc;
    __syncthreads();
    if (tid < 64)
        c0part[(b * QB + qb) * 64 + tid] =
            c0red[0][tid] + c0red[1][tid] + c0red[2][tid] + c0red[3][tid];
}

// ---------------- K2: Jacobi-Richardson solve  G z = c0, lmd = z/dtm ------
// One block (256 thr = 4 waves) per replica. G = sum of partials (SPD,
// diag-dominant: iteration matrix I - D^-1 G has spectral radius ~0.16,
// so 8 iterations leave ~7e-8 relative error, far below bf16-Gram noise).
// One barrier/iter: parity-buffered partials + wave-private z copy.
__global__ __launch_bounds__(256) void k2_solve(const float* __restrict__ Gpart,
                                                const float* __restrict__ c0part,
                                                const float* __restrict__ dtm,
                                                float* __restrict__ lmd_out) {
    __shared__ __align__(16) float G[64][68];
    __shared__ float red[2][4][64];
    __shared__ float zw[4][64];

    const int b = blockIdx.x;
    const int t = threadIdx.x;
    const int i = t & 63, q = t >> 6;

    // reduce the QB Gram partials (float4, coalesced)
    for (int e4 = t * 4; e4 < 4096; e4 += 1024) {
        float4 s = {0.0f, 0.0f, 0.0f, 0.0f};
#pragma unroll
        for (int qq = 0; qq < QB; ++qq) {
            float4 v = *(const float4*)&Gpart[(size_t)(b * QB + qq) * 4096 + e4];
            s.x += v.x; s.y += v.y; s.z += v.z; s.w += v.w;
        }
        *(float4*)&G[e4 >> 6][e4 & 63] = s;
    }
    // c0[i]: every thread (q,i) computes it (waves redundant, identical fp)
    float c0 = 0.0f;
#pragma unroll
    for (int qq = 0; qq < QB; ++qq) c0 += c0part[(b * QB + qq) * 64 + i];
    __syncthreads();  // G ready

    const float invD = 1.0f / G[i][i];
    float z = c0 * invD;          // z0 = D^-1 c0
    zw[q][i] = z;                 // wave-private copy (same-wave read only)

    for (int it = 0; it < 8; ++it) {
        float s = 0.0f;
        const float* gr = &G[i][q * 16];
        const float* zr = &zw[q][q * 16];
#pragma unroll
        for (int g = 0; g < 4; ++g) {
            float4 g4 = *(const float4*)&gr[4 * g];
            float4 z4 = *(const float4*)&zr[4 * g];   // broadcast (same addr/wave)
            s += g4.x * z4.x + g4.y * z4.y + g4.z * z4.z + g4.w * z4.w;
        }
        const int p = it & 1;
        red[p][q][i] = s;
        __syncthreads();  // red[p] complete
        const float rres = c0 - (red[p][0][i] + red[p][1][i] + red[p][2][i] + red[p][3][i]);
        z += rres * invD;         // identical in all 4 waves
        zw[q][i] = z;             // refresh own wave's copy (in-order DS)
    }

    if (t < 64) lmd_out[b * 64 + t] = z * (1.0f / dtm[b]);
}

// ---------------- K3 (fp8): mom_out = mom - dtm * jac8^T lmd --------------
// grid (6, 64), 256 thr. Each thread: 8 k-values; 64 rows x 8B fp8 loads
// (the 50 MB fp8 buffer was written by K1 just before -> L3-resident).
__global__ __launch_bounds__(256) void k3_momout_fp8(const unsigned char* __restrict__ jac8,
                                                     const float* __restrict__ mom,
                                                     const float* __restrict__ dtm,
                                                     const float* __restrict__ lmd,
                                                     float* __restrict__ mom_out) {
    __shared__ float lLds[64];
    const int b   = blockIdx.y;
    const int blk = blockIdx.x;
    const int t   = threadIdx.x;
    if (t < 64) lLds[t] = lmd[b * 64 + t];
    __syncthreads();

    const int kbase = blk * 2048 + t * 8;
    const unsigned char* jp = jac8 + (size_t)b * Cc * Kk + kbase;

    float acc[8];
#pragma unroll
    for (int z = 0; z < 8; ++z) acc[z] = 0.0f;

#pragma unroll 4
    for (int c = 0; c < 64; ++c) {
        uint2 u = *(const uint2*)(jp + (size_t)c * Kk);
        const float lc = lLds[c];
        f32x2 d;
        d = __builtin_amdgcn_cvt_pk_f32_fp8(u.x, false); acc[0] += lc * d[0]; acc[1] += lc * d[1];
        d = __builtin_amdgcn_cvt_pk_f32_fp8(u.x, true);  acc[2] += lc * d[0]; acc[3] += lc * d[1];
        d = __builtin_amdgcn_cvt_pk_f32_fp8(u.y, false); acc[4] += lc * d[0]; acc[5] += lc * d[1];
        d = __builtin_amdgcn_cvt_pk_f32_fp8(u.y, true);  acc[6] += lc * d[0]; acc[7] += lc * d[1];
    }
    const float dt = dtm[b];
    const float* mb = mom + (size_t)b * Kk + kbase;
    float4 m0 = *(const float4*)mb;
    float4 m1 = *(const float4*)(mb + 4);
    float4 o0, o1;
    o0.x = m0.x - dt * acc[0]; o0.y = m0.y - dt * acc[1];
    o0.z = m0.z - dt * acc[2]; o0.w = m0.w - dt * acc[3];
    o1.x = m1.x - dt * acc[4]; o1.y = m1.y - dt * acc[5];
    o1.z = m1.z - dt * acc[6]; o1.w = m1.w - dt * acc[7];
    float* ob = mom_out + (size_t)b * Kk + kbase;
    *(float4*)ob = o0;
    *(float4*)(ob + 4) = o1;
}

// ---------------- K3 (fp32 fallback, ws too small) ------------------------
__global__ __launch_bounds__(256) void k3_momout(const float* __restrict__ jac,
                                                 const float* __restrict__ mom,
                                                 const float* __restrict__ dtm,
                                                 const float* __restrict__ lmd,
                                                 float* __restrict__ mom_out) {
    __shared__ float lLds[64];
    const int b   = blockIdx.y;
    const int blk = blockIdx.x;
    const int t   = threadIdx.x;
    if (t < 64) lLds[t] = lmd[b * 64 + t];
    __syncthreads();

    const size_t kbase = (size_t)blk * 1024 + (size_t)t * 4;
    const float* jp = jac + (size_t)b * Cc * Kk + kbase;

    float4 acc = {0.0f, 0.0f, 0.0f, 0.0f};
#pragma unroll 4
    for (int c = 0; c < 64; ++c) {
        float4 jv = *(const float4*)(jp + (size_t)c * Kk);
        float lc = lLds[c];
        acc.x += lc * jv.x;
        acc.y += lc * jv.y;
        acc.z += lc * jv.z;
        acc.w += lc * jv.w;
    }
    const float dt = dtm[b];
    float4 m4 = *(const float4*)(mom + (size_t)b * Kk + kbase);
    float4 o;
    o.x = m4.x - dt * acc.x;
    o.y = m4.y - dt * acc.y;
    o.z = m4.z - dt * acc.z;
    o.w = m4.w - dt * acc.w;
    *(float4*)(mom_out + (size_t)b * Kk + kbase) = o;
}

extern "C" void kernel_launch(void* const* d_in, const int* in_sizes, int n_in,
                              void* d_out, int out_size, void* d_ws, size_t ws_size,
                              hipStream_t stream) {
    const float* mom = (const float*)d_in[0];
    const float* mas = (const float*)d_in[1];
    const float* dtm = (const float*)d_in[2];
    const float* jac = (const float*)d_in[3];

    float* out = (float*)d_out;            // mom_out: Bb*Kk
    float* lmd = out + (size_t)Bb * Kk;    // lmd: Bb*Cc

    const bool use_fp8 = ws_size >= WS_NEED;

    unsigned char* jac8 = (unsigned char*)d_ws;          // Bb*Cc*Kk bytes
    float* Gpart;
    float* c0part;
    if (use_fp8) {
        Gpart = (float*)(jac8 + J8_BYTES);
        c0part = Gpart + GPART_FLOATS;
    } else {
        Gpart = (float*)d_ws;
        c0part = Gpart + GPART_FLOATS;
    }

    if (use_fp8) {
        k1_gram<true><<<Bb * QB, 256, 0, stream>>>(jac, mas, mom, Gpart, c0part, jac8);
        k2_solve<<<Bb, 256, 0, stream>>>(Gpart, c0part, dtm, lmd);
        k3_momout_fp8<<<dim3(6, 64), 256, 0, stream>>>(jac8, mom, dtm, lmd, out);
    } else {
        k1_gram<false><<<Bb * QB, 256, 0, stream>>>(jac, mas, mom, Gpart, c0part, nullptr);
        k2_solve<<<Bb, 256, 0, stream>>>(Gpart, c0part, dtm, lmd);
        k3_momout<<<dim3(12, 64), 256, 0, stream>>>(jac, mom, dtm, lmd, out);
    }
}

// Round 7
// 65.096 us; speedup vs baseline: 1.6257x; 1.1243x over previous
//
#include <hip/hip_runtime.h>

// Rattle B=64, C=64, N=4096 (K = 12288). out = [mom_out (B*N*3), lmd (B*C)] fp32.
//
// J = -dtm * (W.jac) jac^T  (neg-definite Gram), c0 = (W.jac).mom
// lmd = -J^{-1} c0 = G^{-1} c0 / dtm  with G = (W.jac) jac^T  (SPD, cond ~1.3)
// mom_out = mom - dtm * jac^T lmd
//
// K1: bf16-MFMA partial Grams (fp32 c0 path) + fp8-e4m3 jac copy for K3.
//     QB=8 (R6: QB=16 was -6us), but 512-THREAD blocks (8 waves): wave
//     pairs (w, w+4) split the k-slices of one 32x32 quadrant -> same
//     traffic, half staging work per thread, 4 waves/SIMD instead of 2
//     for latency hiding at the staging vmcnt/barrier waits.
// K2: Jacobi-Richardson solve (rho ~0.16 -> 8 iters; 1 barrier/iter)
// K3: rank-64 momentum update reading the 50 MB fp8 copy (L3-resident)

namespace {
constexpr int Bb = 64;
constexpr int Cc = 64;
constexpr int Kk = 12288;
constexpr int QB = 8;             // K-chunks per replica
constexpr int KCHUNK = Kk / QB;   // 1536
constexpr int NT = KCHUNK / 64;   // 24 tiles of 64 k-floats
constexpr size_t J8_BYTES = (size_t)Bb * Cc * Kk;          // 50,331,648
constexpr size_t GPART_FLOATS = (size_t)Bb * QB * 4096;    // 2,097,152
constexpr size_t C0_FLOATS = (size_t)Bb * QB * 64;         // 32,768
constexpr size_t WS_NEED = J8_BYTES + (GPART_FLOATS + C0_FLOATS) * 4;
}

typedef __attribute__((ext_vector_type(8))) __bf16 bf16x8;
typedef __attribute__((ext_vector_type(16))) float f32x16;
typedef __attribute__((ext_vector_type(2))) float f32x2;

// ---------------- K1: partial Gram via MFMA + fp32 c0 (+ fp8 jac copy) ----
// grid 512 = (b, qb); 512 threads (8 waves). Each block: 64x64 Gram partial
// over a 1536-wide K chunk. LDS bf16 tiles [64 rows][64 k], XOR-swizzled
// (elem ^= (row&7)<<3) so 32-row b128 fragment reads are conflict-free.
// Wave w: quadrant (w&3), k-half (w>>2); pairs reduce via LDS at the end.
template <bool WRITE8>
__global__ __launch_bounds__(512) void k1_gram(const float* __restrict__ jac,
                                               const float* __restrict__ mas,
                                               const float* __restrict__ mom,
                                               float* __restrict__ Gpart,
                                               float* __restrict__ c0part,
                                               unsigned char* __restrict__ jac8) {
    __shared__ __align__(16) __bf16 AhL[64 * 64];   // bf16(w * jac)
    __shared__ __align__(16) __bf16 BhL[64 * 64];   // bf16(jac)
    __shared__ __align__(16) float wLds[KCHUNK];
    __shared__ float c0red[8][64];
    __shared__ float accred[4][64][17];             // pad 17: no bank conflicts

    const int b   = blockIdx.x >> 3;
    const int qb  = blockIdx.x & 7;
    const int tid = threadIdx.x;
    const int kbeg = qb * KCHUNK;

    // per-chunk weights w = 1/mas (fp32, exact-path for c0)
    for (int kk = tid; kk < KCHUNK; kk += 512)
        wLds[kk] = 1.0f / mas[b * 4096 + (kbeg + kk) / 3];

    // staging map: row cS (0..63), 8-k segment gS (0..7)
    const int cS = tid >> 3, gS = tid & 7;
    const float* jrow = jac + (size_t)(b * 64 + cS) * Kk;
    const float* momB = mom + (size_t)b * Kk;
    unsigned char* j8row = jac8 + (size_t)(b * 64 + cS) * Kk;  // byte/elem
    const int swzS = (cS & 7) << 3;

    // MFMA map: wave w -> quadrant qd=(w&3) -> (i0,j0); khalf=(w>>2) k-split
    const int w = tid >> 6, lane = tid & 63;
    const int qd = w & 3, khalf = w >> 2;
    const int i0 = (qd & 1) << 5, j0 = (qd >> 1) << 5;
    const int r = lane & 31, kg = lane >> 5;
    const int arow = i0 + r, brow = j0 + r;
    const int abase = arow * 64, aswz = (arow & 7) << 3;
    const int bbase = brow * 64, bswz = (brow & 7) << 3;

    f32x16 acc;
#pragma unroll
    for (int z = 0; z < 16; ++z) acc[z] = 0.0f;
    float c0acc = 0.0f;

    __syncthreads();  // wLds ready

    for (int t = 0; t < NT; ++t) {
        const int k0 = kbeg + t * 64;
        const float4* jp = (const float4*)(jrow + k0 + gS * 8);
        const float4* wp = (const float4*)(wLds + (k0 - kbeg) + gS * 8);
        const float4* mp = (const float4*)(momB + k0 + gS * 8);

        bf16x8 ah, bh;
        int pk[2];
#pragma unroll
        for (int v = 0; v < 2; ++v) {
            float4 x = jp[v];
            float4 wv = wp[v];
            float4 m = mp[v];
            float y0 = x.x * wv.x, y1 = x.y * wv.y, y2 = x.z * wv.z, y3 = x.w * wv.w;
            c0acc += y0 * m.x + y1 * m.y + y2 * m.z + y3 * m.w;
            const int e0 = v * 4;
            ah[e0 + 0] = (__bf16)y0; ah[e0 + 1] = (__bf16)y1;
            ah[e0 + 2] = (__bf16)y2; ah[e0 + 3] = (__bf16)y3;
            bh[e0 + 0] = (__bf16)x.x; bh[e0 + 1] = (__bf16)x.y;
            bh[e0 + 2] = (__bf16)x.z; bh[e0 + 3] = (__bf16)x.w;
            if (WRITE8) {
                int lo = __builtin_amdgcn_cvt_pk_fp8_f32(x.x, x.y, 0, false);
                pk[v]  = __builtin_amdgcn_cvt_pk_fp8_f32(x.z, x.w, lo, true);
            }
        }
        if (WRITE8) {
            uint2 u = {(unsigned)pk[0], (unsigned)pk[1]};
            *(uint2*)(j8row + k0 + gS * 8) = u;
        }
        {
            const int off = cS * 64 + ((gS * 8) ^ swzS);
            *(bf16x8*)&AhL[off] = ah;
            *(bf16x8*)&BhL[off] = bh;
        }
        __syncthreads();

#pragma unroll
        for (int s = 0; s < 2; ++s) {
            const int ks = khalf * 2 + s;
            const int kc = ks * 16 + kg * 8;
            bf16x8 a  = *(const bf16x8*)&AhL[abase + (kc ^ aswz)];
            bf16x8 bb = *(const bf16x8*)&BhL[bbase + (kc ^ bswz)];
            acc = __builtin_amdgcn_mfma_f32_32x32x16_bf16(a, bb, acc, 0, 0, 0);
        }
        __syncthreads();
    }

    // cross-wave k-half reduction: waves 4-7 stash, waves 0-3 add + write.
    if (khalf == 1) {
#pragma unroll
        for (int z = 0; z < 16; ++z) accred[qd][lane][z] = acc[z];
    }
    c0red[gS][cS] = c0acc;
    __syncthreads();

    if (khalf == 0) {
        // C/D layout (m74/m101): col = lane&31, row = (reg&3)+8*(reg>>2)+4*(lane>>5)
        float* Gp = Gpart + (size_t)(b * QB + qb) * 4096;
#pragma unroll
        for (int reg = 0; reg < 16; ++reg) {
            const int row = (reg & 3) + 8 * (reg >> 2) + 4 * kg;
            Gp[(i0 + row) * 64 + (j0 + r)] = acc[reg] + accred[qd][lane][reg];
        }
    }
    if (tid < 64) {
        float s = 0.0f;
#pragma unroll
        for (int g = 0; g < 8; ++g) s += c0red[g][tid];
        c0part[(b * QB + qb) * 64 + tid] = s;
    }
}

// ---------------- K2: Jacobi-Richardson solve  G z = c0, lmd = z/dtm ------
// One block (256 thr = 4 waves) per replica. G = sum of partials (SPD,
// diag-dominant: iteration matrix I - D^-1 G has spectral radius ~0.16,
// so 8 iterations leave ~7e-8 relative error, far below bf16-Gram noise).
// One barrier/iter: parity-buffered partials + wave-private z copy.
__global__ __launch_bounds__(256) void k2_solve(const float* __restrict__ Gpart,
                                                const float* __restrict__ c0part,
                                                const float* __restrict__ dtm,
                                                float* __restrict__ lmd_out) {
    __shared__ __align__(16) float G[64][68];
    __shared__ float red[2][4][64];
    __shared__ float zw[4][64];

    const int b = blockIdx.x;
    const int t = threadIdx.x;
    const int i = t & 63, q = t >> 6;

    // reduce the QB Gram partials (float4, coalesced)
    for (int e4 = t * 4; e4 < 4096; e4 += 1024) {
        float4 s = {0.0f, 0.0f, 0.0f, 0.0f};
#pragma unroll
        for (int qq = 0; qq < QB; ++qq) {
            float4 v = *(const float4*)&Gpart[(size_t)(b * QB + qq) * 4096 + e4];
            s.x += v.x; s.y += v.y; s.z += v.z; s.w += v.w;
        }
        *(float4*)&G[e4 >> 6][e4 & 63] = s;
    }
    // c0[i]: every thread (q,i) computes it (waves redundant, identical fp)
    float c0 = 0.0f;
#pragma unroll
    for (int qq = 0; qq < QB; ++qq) c0 += c0part[(b * QB + qq) * 64 + i];
    __syncthreads();  // G ready

    const float invD = 1.0f / G[i][i];
    float z = c0 * invD;          // z0 = D^-1 c0
    zw[q][i] = z;                 // wave-private copy (same-wave read only)

    for (int it = 0; it < 8; ++it) {
        float s = 0.0f;
        const float* gr = &G[i][q * 16];
        const float* zr = &zw[q][q * 16];
#pragma unroll
        for (int g = 0; g < 4; ++g) {
            float4 g4 = *(const float4*)&gr[4 * g];
            float4 z4 = *(const float4*)&zr[4 * g];   // broadcast (same addr/wave)
            s += g4.x * z4.x + g4.y * z4.y + g4.z * z4.z + g4.w * z4.w;
        }
        const int p = it & 1;
        red[p][q][i] = s;
        __syncthreads();  // red[p] complete
        const float rres = c0 - (red[p][0][i] + red[p][1][i] + red[p][2][i] + red[p][3][i]);
        z += rres * invD;         // identical in all 4 waves
        zw[q][i] = z;             // refresh own wave's copy (in-order DS)
    }

    if (t < 64) lmd_out[b * 64 + t] = z * (1.0f / dtm[b]);
}

// ---------------- K3 (fp8): mom_out = mom - dtm * jac8^T lmd --------------
// grid (6, 64), 256 thr. Each thread: 8 k-values; 64 rows x 8B fp8 loads
// (the 50 MB fp8 buffer was written by K1 just before -> L3-resident).
__global__ __launch_bounds__(256) void k3_momout_fp8(const unsigned char* __restrict__ jac8,
                                                     const float* __restrict__ mom,
                                                     const float* __restrict__ dtm,
                                                     const float* __restrict__ lmd,
                                                     float* __restrict__ mom_out) {
    __shared__ float lLds[64];
    const int b   = blockIdx.y;
    const int blk = blockIdx.x;
    const int t   = threadIdx.x;
    if (t < 64) lLds[t] = lmd[b * 64 + t];
    __syncthreads();

    const int kbase = blk * 2048 + t * 8;
    const unsigned char* jp = jac8 + (size_t)b * Cc * Kk + kbase;

    float acc[8];
#pragma unroll
    for (int z = 0; z < 8; ++z) acc[z] = 0.0f;

#pragma unroll 4
    for (int c = 0; c < 64; ++c) {
        uint2 u = *(const uint2*)(jp + (size_t)c * Kk);
        const float lc = lLds[c];
        f32x2 d;
        d = __builtin_amdgcn_cvt_pk_f32_fp8(u.x, false); acc[0] += lc * d[0]; acc[1] += lc * d[1];
        d = __builtin_amdgcn_cvt_pk_f32_fp8(u.x, true);  acc[2] += lc * d[0]; acc[3] += lc * d[1];
        d = __builtin_amdgcn_cvt_pk_f32_fp8(u.y, false); acc[4] += lc * d[0]; acc[5] += lc * d[1];
        d = __builtin_amdgcn_cvt_pk_f32_fp8(u.y, true);  acc[6] += lc * d[0]; acc[7] += lc * d[1];
    }
    const float dt = dtm[b];
    const float* mb = mom + (size_t)b * Kk + kbase;
    float4 m0 = *(const float4*)mb;
    float4 m1 = *(const float4*)(mb + 4);
    float4 o0, o1;
    o0.x = m0.x - dt * acc[0]; o0.y = m0.y - dt * acc[1];
    o0.z = m0.z - dt * acc[2]; o0.w = m0.w - dt * acc[3];
    o1.x = m1.x - dt * acc[4]; o1.y = m1.y - dt * acc[5];
    o1.z = m1.z - dt * acc[6]; o1.w = m1.w - dt * acc[7];
    float* ob = mom_out + (size_t)b * Kk + kbase;
    *(float4*)ob = o0;
    *(float4*)(ob + 4) = o1;
}

// ---------------- K3 (fp32 fallback, ws too small) ------------------------
__global__ __launch_bounds__(256) void k3_momout(const float* __restrict__ jac,
                                                 const float* __restrict__ mom,
                                                 const float* __restrict__ dtm,
                                                 const float* __restrict__ lmd,
                                                 float* __restrict__ mom_out) {
    __shared__ float lLds[64];
    const int b   = blockIdx.y;
    const int blk = blockIdx.x;
    const int t   = threadIdx.x;
    if (t < 64) lLds[t] = lmd[b * 64 + t];
    __syncthreads();

    const size_t kbase = (size_t)blk * 1024 + (size_t)t * 4;
    const float* jp = jac + (size_t)b * Cc * Kk + kbase;

    float4 acc = {0.0f, 0.0f, 0.0f, 0.0f};
#pragma unroll 4
    for (int c = 0; c < 64; ++c) {
        float4 jv = *(const float4*)(jp + (size_t)c * Kk);
        float lc = lLds[c];
        acc.x += lc * jv.x;
        acc.y += lc * jv.y;
        acc.z += lc * jv.z;
        acc.w += lc * jv.w;
    }
    const float dt = dtm[b];
    float4 m4 = *(const float4*)(mom + (size_t)b * Kk + kbase);
    float4 o;
    o.x = m4.x - dt * acc.x;
    o.y = m4.y - dt * acc.y;
    o.z = m4.z - dt * acc.z;
    o.w = m4.w - dt * acc.w;
    *(float4*)(mom_out + (size_t)b * Kk + kbase) = o;
}

extern "C" void kernel_launch(void* const* d_in, const int* in_sizes, int n_in,
                              void* d_out, int out_size, void* d_ws, size_t ws_size,
                              hipStream_t stream) {
    const float* mom = (const float*)d_in[0];
    const float* mas = (const float*)d_in[1];
    const float* dtm = (const float*)d_in[2];
    const float* jac = (const float*)d_in[3];

    float* out = (float*)d_out;            // mom_out: Bb*Kk
    float* lmd = out + (size_t)Bb * Kk;    // lmd: Bb*Cc

    const bool use_fp8 = ws_size >= WS_NEED;

    unsigned char* jac8 = (unsigned char*)d_ws;          // Bb*Cc*Kk bytes
    float* Gpart;
    float* c0part;
    if (use_fp8) {
        Gpart = (float*)(jac8 + J8_BYTES);
        c0part = Gpart + GPART_FLOATS;
    } else {
        Gpart = (float*)d_ws;
        c0part = Gpart + GPART_FLOATS;
    }

    if (use_fp8) {
        k1_gram<true><<<Bb * QB, 512, 0, stream>>>(jac, mas, mom, Gpart, c0part, jac8);
        k2_solve<<<Bb, 256, 0, stream>>>(Gpart, c0part, dtm, lmd);
        k3_momout_fp8<<<dim3(6, 64), 256, 0, stream>>>(jac8, mom, dtm, lmd, out);
    } else {
        k1_gram<false><<<Bb * QB, 512, 0, stream>>>(jac, mas, mom, Gpart, c0part, nullptr);
        k2_solve<<<Bb, 256, 0, stream>>>(Gpart, c0part, dtm, lmd);
        k3_momout<<<dim3(12, 64), 256, 0, stream>>>(jac, mom, dtm, lmd, out);
    }
}

// Round 8
// 63.912 us; speedup vs baseline: 1.6558x; 1.0185x over previous
//
#include <hip/hip_runtime.h>

// Rattle B=64, C=64, N=4096 (K = 12288). out = [mom_out (B*N*3), lmd (B*C)] fp32.
//
// J = -dtm * (W.jac) jac^T  (neg-definite Gram), c0 = (W.jac).mom
// lmd = -J^{-1} c0 = G^{-1} c0 / dtm  with G = (W.jac) jac^T  (SPD, cond ~1.3)
// mom_out = mom - dtm * jac^T lmd
//
// K1: bf16-MFMA partial Grams (fp32 c0 path) + fp8-e4m3 jac copy for K3.
//     512-thread blocks (R7: 4 waves/SIMD), QB=8. LDS bf16 tiles are
//     DOUBLE-BUFFERED -> ONE __syncthreads per k-tile (24+1 barriers vs
//     48): write buf[t&1], barrier, MFMA-read buf[t&1]; the next write
//     to a buffer is two barriers after its last read (safe).
// K2: Jacobi-Richardson solve (rho ~0.16 -> 6 iters; 1 barrier/iter)
// K3: rank-64 momentum update reading the 50 MB fp8 copy (L3-resident)

namespace {
constexpr int Bb = 64;
constexpr int Cc = 64;
constexpr int Kk = 12288;
constexpr int QB = 8;             // K-chunks per replica
constexpr int KCHUNK = Kk / QB;   // 1536
constexpr int NT = KCHUNK / 64;   // 24 tiles of 64 k-floats
constexpr size_t J8_BYTES = (size_t)Bb * Cc * Kk;          // 50,331,648
constexpr size_t GPART_FLOATS = (size_t)Bb * QB * 4096;    // 2,097,152
constexpr size_t C0_FLOATS = (size_t)Bb * QB * 64;         // 32,768
constexpr size_t WS_NEED = J8_BYTES + (GPART_FLOATS + C0_FLOATS) * 4;
}

typedef __attribute__((ext_vector_type(8))) __bf16 bf16x8;
typedef __attribute__((ext_vector_type(16))) float f32x16;
typedef __attribute__((ext_vector_type(2))) float f32x2;

// ---------------- K1: partial Gram via MFMA + fp32 c0 (+ fp8 jac copy) ----
// grid 512 = (b, qb); 512 threads (8 waves). Each block: 64x64 Gram partial
// over a 1536-wide K chunk. LDS bf16 tiles [64 rows][64 k], XOR-swizzled
// (elem ^= (row&7)<<3) so 32-row b128 fragment reads are conflict-free.
// Wave w: quadrant (w&3), k-half (w>>2); pairs reduce via LDS at the end.
template <bool WRITE8>
__global__ __launch_bounds__(512) void k1_gram(const float* __restrict__ jac,
                                               const float* __restrict__ mas,
                                               const float* __restrict__ mom,
                                               float* __restrict__ Gpart,
                                               float* __restrict__ c0part,
                                               unsigned char* __restrict__ jac8) {
    __shared__ __align__(16) __bf16 AhL[2][64 * 64];   // bf16(w * jac), dbuf
    __shared__ __align__(16) __bf16 BhL[2][64 * 64];   // bf16(jac), dbuf
    __shared__ __align__(16) float wLds[KCHUNK];
    __shared__ float c0red[8][64];
    __shared__ float accred[4][64][17];             // pad 17: no bank conflicts

    const int b   = blockIdx.x >> 3;
    const int qb  = blockIdx.x & 7;
    const int tid = threadIdx.x;
    const int kbeg = qb * KCHUNK;

    // per-chunk weights w = 1/mas (fp32, exact-path for c0)
    for (int kk = tid; kk < KCHUNK; kk += 512)
        wLds[kk] = 1.0f / mas[b * 4096 + (kbeg + kk) / 3];

    // staging map: row cS (0..63), 8-k segment gS (0..7)
    const int cS = tid >> 3, gS = tid & 7;
    const float* jrow = jac + (size_t)(b * 64 + cS) * Kk;
    const float* momB = mom + (size_t)b * Kk;
    unsigned char* j8row = jac8 + (size_t)(b * 64 + cS) * Kk;  // byte/elem
    const int swzS = (cS & 7) << 3;

    // MFMA map: wave w -> quadrant qd=(w&3) -> (i0,j0); khalf=(w>>2) k-split
    const int w = tid >> 6, lane = tid & 63;
    const int qd = w & 3, khalf = w >> 2;
    const int i0 = (qd & 1) << 5, j0 = (qd >> 1) << 5;
    const int r = lane & 31, kg = lane >> 5;
    const int arow = i0 + r, brow = j0 + r;
    const int abase = arow * 64, aswz = (arow & 7) << 3;
    const int bbase = brow * 64, bswz = (brow & 7) << 3;

    f32x16 acc;
#pragma unroll
    for (int z = 0; z < 16; ++z) acc[z] = 0.0f;
    float c0acc = 0.0f;

    __syncthreads();  // wLds ready

    for (int t = 0; t < NT; ++t) {
        const int p = t & 1;
        const int k0 = kbeg + t * 64;
        const float4* jp = (const float4*)(jrow + k0 + gS * 8);
        const float4* wp = (const float4*)(wLds + (k0 - kbeg) + gS * 8);
        const float4* mp = (const float4*)(momB + k0 + gS * 8);

        bf16x8 ah, bh;
        int pk[2];
#pragma unroll
        for (int v = 0; v < 2; ++v) {
            float4 x = jp[v];
            float4 wv = wp[v];
            float4 m = mp[v];
            float y0 = x.x * wv.x, y1 = x.y * wv.y, y2 = x.z * wv.z, y3 = x.w * wv.w;
            c0acc += y0 * m.x + y1 * m.y + y2 * m.z + y3 * m.w;
            const int e0 = v * 4;
            ah[e0 + 0] = (__bf16)y0; ah[e0 + 1] = (__bf16)y1;
            ah[e0 + 2] = (__bf16)y2; ah[e0 + 3] = (__bf16)y3;
            bh[e0 + 0] = (__bf16)x.x; bh[e0 + 1] = (__bf16)x.y;
            bh[e0 + 2] = (__bf16)x.z; bh[e0 + 3] = (__bf16)x.w;
            if (WRITE8) {
                int lo = __builtin_amdgcn_cvt_pk_fp8_f32(x.x, x.y, 0, false);
                pk[v]  = __builtin_amdgcn_cvt_pk_fp8_f32(x.z, x.w, lo, true);
            }
        }
        if (WRITE8) {
            uint2 u = {(unsigned)pk[0], (unsigned)pk[1]};
            *(uint2*)(j8row + k0 + gS * 8) = u;
        }
        {
            const int off = cS * 64 + ((gS * 8) ^ swzS);
            *(bf16x8*)&AhL[p][off] = ah;
            *(bf16x8*)&BhL[p][off] = bh;
        }
        __syncthreads();  // buf[p] published; prior reads of buf[p] were 2 barriers ago

#pragma unroll
        for (int s = 0; s < 2; ++s) {
            const int ks = khalf * 2 + s;
            const int kc = ks * 16 + kg * 8;
            bf16x8 a  = *(const bf16x8*)&AhL[p][abase + (kc ^ aswz)];
            bf16x8 bb = *(const bf16x8*)&BhL[p][bbase + (kc ^ bswz)];
            acc = __builtin_amdgcn_mfma_f32_32x32x16_bf16(a, bb, acc, 0, 0, 0);
        }
        // no second barrier: next tile writes the other buffer
    }

    __syncthreads();  // last tile's reads done before epilogue LDS reuse

    // cross-wave k-half reduction: waves 4-7 stash, waves 0-3 add + write.
    if (khalf == 1) {
#pragma unroll
        for (int z = 0; z < 16; ++z) accred[qd][lane][z] = acc[z];
    }
    c0red[gS][cS] = c0acc;
    __syncthreads();

    if (khalf == 0) {
        // C/D layout (m74/m101): col = lane&31, row = (reg&3)+8*(reg>>2)+4*(lane>>5)
        float* Gp = Gpart + (size_t)(b * QB + qb) * 4096;
#pragma unroll
        for (int reg = 0; reg < 16; ++reg) {
            const int row = (reg & 3) + 8 * (reg >> 2) + 4 * kg;
            Gp[(i0 + row) * 64 + (j0 + r)] = acc[reg] + accred[qd][lane][reg];
        }
    }
    if (tid < 64) {
        float s = 0.0f;
#pragma unroll
        for (int g = 0; g < 8; ++g) s += c0red[g][tid];
        c0part[(b * QB + qb) * 64 + tid] = s;
    }
}

// ---------------- K2: Jacobi-Richardson solve  G z = c0, lmd = z/dtm ------
// One block (256 thr = 4 waves) per replica. G = sum of partials (SPD,
// diag-dominant: iteration matrix I - D^-1 G has spectral radius ~0.16,
// so 6 iterations leave ~4e-6 relative error, far below bf16-Gram noise).
// One barrier/iter: parity-buffered partials + wave-private z copy.
__global__ __launch_bounds__(256) void k2_solve(const float* __restrict__ Gpart,
                                                const float* __restrict__ c0part,
                                                const float* __restrict__ dtm,
                                                float* __restrict__ lmd_out) {
    __shared__ __align__(16) float G[64][68];
    __shared__ float red[2][4][64];
    __shared__ float zw[4][64];

    const int b = blockIdx.x;
    const int t = threadIdx.x;
    const int i = t & 63, q = t >> 6;

    // reduce the QB Gram partials (float4, coalesced)
    for (int e4 = t * 4; e4 < 4096; e4 += 1024) {
        float4 s = {0.0f, 0.0f, 0.0f, 0.0f};
#pragma unroll
        for (int qq = 0; qq < QB; ++qq) {
            float4 v = *(const float4*)&Gpart[(size_t)(b * QB + qq) * 4096 + e4];
            s.x += v.x; s.y += v.y; s.z += v.z; s.w += v.w;
        }
        *(float4*)&G[e4 >> 6][e4 & 63] = s;
    }
    // c0[i]: every thread (q,i) computes it (waves redundant, identical fp)
    float c0 = 0.0f;
#pragma unroll
    for (int qq = 0; qq < QB; ++qq) c0 += c0part[(b * QB + qq) * 64 + i];
    __syncthreads();  // G ready

    const float invD = 1.0f / G[i][i];
    float z = c0 * invD;          // z0 = D^-1 c0
    zw[q][i] = z;                 // wave-private copy (same-wave read only)

    for (int it = 0; it < 6; ++it) {
        float s = 0.0f;
        const float* gr = &G[i][q * 16];
        const float* zr = &zw[q][q * 16];
#pragma unroll
        for (int g = 0; g < 4; ++g) {
            float4 g4 = *(const float4*)&gr[4 * g];
            float4 z4 = *(const float4*)&zr[4 * g];   // broadcast (same addr/wave)
            s += g4.x * z4.x + g4.y * z4.y + g4.z * z4.z + g4.w * z4.w;
        }
        const int p = it & 1;
        red[p][q][i] = s;
        __syncthreads();  // red[p] complete
        const float rres = c0 - (red[p][0][i] + red[p][1][i] + red[p][2][i] + red[p][3][i]);
        z += rres * invD;         // identical in all 4 waves
        zw[q][i] = z;             // refresh own wave's copy (in-order DS)
    }

    if (t < 64) lmd_out[b * 64 + t] = z * (1.0f / dtm[b]);
}

// ---------------- K3 (fp8): mom_out = mom - dtm * jac8^T lmd --------------
// grid (6, 64), 256 thr. Each thread: 8 k-values; 64 rows x 8B fp8 loads
// (the 50 MB fp8 buffer was written by K1 just before -> L3-resident).
__global__ __launch_bounds__(256) void k3_momout_fp8(const unsigned char* __restrict__ jac8,
                                                     const float* __restrict__ mom,
                                                     const float* __restrict__ dtm,
                                                     const float* __restrict__ lmd,
                                                     float* __restrict__ mom_out) {
    __shared__ float lLds[64];
    const int b   = blockIdx.y;
    const int blk = blockIdx.x;
    const int t   = threadIdx.x;
    if (t < 64) lLds[t] = lmd[b * 64 + t];
    __syncthreads();

    const int kbase = blk * 2048 + t * 8;
    const unsigned char* jp = jac8 + (size_t)b * Cc * Kk + kbase;

    float acc[8];
#pragma unroll
    for (int z = 0; z < 8; ++z) acc[z] = 0.0f;

#pragma unroll 4
    for (int c = 0; c < 64; ++c) {
        uint2 u = *(const uint2*)(jp + (size_t)c * Kk);
        const float lc = lLds[c];
        f32x2 d;
        d = __builtin_amdgcn_cvt_pk_f32_fp8(u.x, false); acc[0] += lc * d[0]; acc[1] += lc * d[1];
        d = __builtin_amdgcn_cvt_pk_f32_fp8(u.x, true);  acc[2] += lc * d[0]; acc[3] += lc * d[1];
        d = __builtin_amdgcn_cvt_pk_f32_fp8(u.y, false); acc[4] += lc * d[0]; acc[5] += lc * d[1];
        d = __builtin_amdgcn_cvt_pk_f32_fp8(u.y, true);  acc[6] += lc * d[0]; acc[7] += lc * d[1];
    }
    const float dt = dtm[b];
    const float* mb = mom + (size_t)b * Kk + kbase;
    float4 m0 = *(const float4*)mb;
    float4 m1 = *(const float4*)(mb + 4);
    float4 o0, o1;
    o0.x = m0.x - dt * acc[0]; o0.y = m0.y - dt * acc[1];
    o0.z = m0.z - dt * acc[2]; o0.w = m0.w - dt * acc[3];
    o1.x = m1.x - dt * acc[4]; o1.y = m1.y - dt * acc[5];
    o1.z = m1.z - dt * acc[6]; o1.w = m1.w - dt * acc[7];
    float* ob = mom_out + (size_t)b * Kk + kbase;
    *(float4*)ob = o0;
    *(float4*)(ob + 4) = o1;
}

// ---------------- K3 (fp32 fallback, ws too small) ------------------------
__global__ __launch_bounds__(256) void k3_momout(const float* __restrict__ jac,
                                                 const float* __restrict__ mom,
                                                 const float* __restrict__ dtm,
                                                 const float* __restrict__ lmd,
                                                 float* __restrict__ mom_out) {
    __shared__ float lLds[64];
    const int b   = blockIdx.y;
    const int blk = blockIdx.x;
    const int t   = threadIdx.x;
    if (t < 64) lLds[t] = lmd[b * 64 + t];
    __syncthreads();

    const size_t kbase = (size_t)blk * 1024 + (size_t)t * 4;
    const float* jp = jac + (size_t)b * Cc * Kk + kbase;

    float4 acc = {0.0f, 0.0f, 0.0f, 0.0f};
#pragma unroll 4
    for (int c = 0; c < 64; ++c) {
        float4 jv = *(const float4*)(jp + (size_t)c * Kk);
        float lc = lLds[c];
        acc.x += lc * jv.x;
        acc.y += lc * jv.y;
        acc.z += lc * jv.z;
        acc.w += lc * jv.w;
    }
    const float dt = dtm[b];
    float4 m4 = *(const float4*)(mom + (size_t)b * Kk + kbase);
    float4 o;
    o.x = m4.x - dt * acc.x;
    o.y = m4.y - dt * acc.y;
    o.z = m4.z - dt * acc.z;
    o.w = m4.w - dt * acc.w;
    *(float4*)(mom_out + (size_t)b * Kk + kbase) = o;
}

extern "C" void kernel_launch(void* const* d_in, const int* in_sizes, int n_in,
                              void* d_out, int out_size, void* d_ws, size_t ws_size,
                              hipStream_t stream) {
    const float* mom = (const float*)d_in[0];
    const float* mas = (const float*)d_in[1];
    const float* dtm = (const float*)d_in[2];
    const float* jac = (const float*)d_in[3];

    float* out = (float*)d_out;            // mom_out: Bb*Kk
    float* lmd = out + (size_t)Bb * Kk;    // lmd: Bb*Cc

    const bool use_fp8 = ws_size >= WS_NEED;

    unsigned char* jac8 = (unsigned char*)d_ws;          // Bb*Cc*Kk bytes
    float* Gpart;
    float* c0part;
    if (use_fp8) {
        Gpart = (float*)(jac8 + J8_BYTES);
        c0part = Gpart + GPART_FLOATS;
    } else {
        Gpart = (float*)d_ws;
        c0part = Gpart + GPART_FLOATS;
    }

    if (use_fp8) {
        k1_gram<true><<<Bb * QB, 512, 0, stream>>>(jac, mas, mom, Gpart, c0part, jac8);
        k2_solve<<<Bb, 256, 0, stream>>>(Gpart, c0part, dtm, lmd);
        k3_momout_fp8<<<dim3(6, 64), 256, 0, stream>>>(jac8, mom, dtm, lmd, out);
    } else {
        k1_gram<false><<<Bb * QB, 512, 0, stream>>>(jac, mas, mom, Gpart, c0part, nullptr);
        k2_solve<<<Bb, 256, 0, stream>>>(Gpart, c0part, dtm, lmd);
        k3_momout<<<dim3(12, 64), 256, 0, stream>>>(jac, mom, dtm, lmd, out);
    }
}

// Round 9
// 62.977 us; speedup vs baseline: 1.6804x; 1.0148x over previous
//
#include <hip/hip_runtime.h>

// Rattle B=64, C=64, N=4096 (K = 12288). out = [mom_out (B*N*3), lmd (B*C)] fp32.
//
// J = -dtm * (W.jac) jac^T  (neg-definite Gram), c0 = (W.jac).mom
// lmd = -J^{-1} c0 = G^{-1} c0 / dtm  with G = (W.jac) jac^T  (SPD, cond ~1.3)
// mom_out = mom - dtm * jac^T lmd
//
// K1: bf16-MFMA partial Grams (fp32 c0 path) + fp8-e4m3 jac copy for K3.
//     512-thread blocks (4 waves/SIMD, R7), QB=8, 128-wide k-tiles (R9):
//     12 double-buffered tiles, ONE barrier each (13 total vs 25), 64 B
//     staged per thread per phase -> 2x deeper load queue per barrier.
//     Epilogue LDS (accred/c0red) overlays the dead tile buffers.
// K2: Jacobi-Richardson solve (rho ~0.16 -> 6 iters; 1 barrier/iter)
// K3: rank-64 momentum update reading the 50 MB fp8 copy (L3-resident)

namespace {
constexpr int Bb = 64;
constexpr int Cc = 64;
constexpr int Kk = 12288;
constexpr int QB = 8;             // K-chunks per replica
constexpr int KCHUNK = Kk / QB;   // 1536
constexpr int TW = 128;           // k-tile width
constexpr int NT = KCHUNK / TW;   // 12 tiles
constexpr size_t J8_BYTES = (size_t)Bb * Cc * Kk;          // 50,331,648
constexpr size_t GPART_FLOATS = (size_t)Bb * QB * 4096;    // 2,097,152
constexpr size_t C0_FLOATS = (size_t)Bb * QB * 64;         // 32,768
constexpr size_t WS_NEED = J8_BYTES + (GPART_FLOATS + C0_FLOATS) * 4;
}

typedef __attribute__((ext_vector_type(8))) __bf16 bf16x8;
typedef __attribute__((ext_vector_type(16))) float f32x16;
typedef __attribute__((ext_vector_type(2))) float f32x2;

// ---------------- K1: partial Gram via MFMA + fp32 c0 (+ fp8 jac copy) ----
// grid 512 = (b, qb); 512 threads (8 waves). Each block: 64x64 Gram partial
// over a 1536-wide K chunk. LDS bf16 tiles [64 rows][128 k], XOR-swizzled
// (elem ^= (row&7)<<3) so 32-row b128 fragment reads keep the R8-proven
// bank profile. Wave w: quadrant (w&3), k-half (w>>2); pairs LDS-reduce.
template <bool WRITE8>
__global__ __launch_bounds__(512) void k1_gram(const float* __restrict__ jac,
                                               const float* __restrict__ mas,
                                               const float* __restrict__ mom,
                                               float* __restrict__ Gpart,
                                               float* __restrict__ c0part,
                                               unsigned char* __restrict__ jac8) {
    __shared__ __align__(16) __bf16 AhL[2][64 * TW];   // bf16(w * jac), dbuf (32 KB)
    __shared__ __align__(16) __bf16 BhL[2][64 * TW];   // bf16(jac), dbuf (32 KB)
    __shared__ __align__(16) float wLds[KCHUNK];       // 6 KB

    // epilogue-only scratch, overlaid on dead tile buffers (post-loop barrier)
    float (*accred)[64][17] = reinterpret_cast<float (*)[64][17]>(&AhL[0][0]); // [4][64][17] 17.4 KB
    float (*c0red)[64]      = reinterpret_cast<float (*)[64]>(&BhL[0][0]);     // [8][64] 2 KB

    const int b   = blockIdx.x >> 3;
    const int qb  = blockIdx.x & 7;
    const int tid = threadIdx.x;
    const int kbeg = qb * KCHUNK;

    // per-chunk weights w = 1/mas (fp32, exact-path for c0)
    for (int kk = tid; kk < KCHUNK; kk += 512)
        wLds[kk] = 1.0f / mas[b * 4096 + (kbeg + kk) / 3];

    // staging map: row cS (0..63), 16-float segment gS (0..7)
    const int cS = tid >> 3, gS = tid & 7;
    const float* jrow = jac + (size_t)(b * 64 + cS) * Kk;
    const float* momB = mom + (size_t)b * Kk;
    unsigned char* j8row = jac8 + (size_t)(b * 64 + cS) * Kk;  // byte/elem
    const int swzS = (cS & 7) << 3;

    // MFMA map: wave w -> quadrant qd=(w&3) -> (i0,j0); khalf=(w>>2) k-split
    const int w = tid >> 6, lane = tid & 63;
    const int qd = w & 3, khalf = w >> 2;
    const int i0 = (qd & 1) << 5, j0 = (qd >> 1) << 5;
    const int r = lane & 31, kg = lane >> 5;
    const int arow = i0 + r, brow = j0 + r;
    const int abase = arow * TW, aswz = (arow & 7) << 3;
    const int bbase = brow * TW, bswz = (brow & 7) << 3;

    f32x16 acc;
#pragma unroll
    for (int z = 0; z < 16; ++z) acc[z] = 0.0f;
    float c0acc = 0.0f;

    __syncthreads();  // wLds ready

    for (int t = 0; t < NT; ++t) {
        const int p = t & 1;
        const int k0 = kbeg + t * TW;
        const float4* jp = (const float4*)(jrow + k0 + gS * 16);
        const float4* wp = (const float4*)(wLds + (k0 - kbeg) + gS * 16);
        const float4* mp = (const float4*)(momB + k0 + gS * 16);

        bf16x8 ah[2], bh[2];
        int pk[4];
#pragma unroll
        for (int v = 0; v < 4; ++v) {
            float4 x = jp[v];
            float4 wv = wp[v];
            float4 m = mp[v];
            float y0 = x.x * wv.x, y1 = x.y * wv.y, y2 = x.z * wv.z, y3 = x.w * wv.w;
            c0acc += y0 * m.x + y1 * m.y + y2 * m.z + y3 * m.w;
            const int h = v >> 1, e0 = (v & 1) * 4;
            ah[h][e0 + 0] = (__bf16)y0; ah[h][e0 + 1] = (__bf16)y1;
            ah[h][e0 + 2] = (__bf16)y2; ah[h][e0 + 3] = (__bf16)y3;
            bh[h][e0 + 0] = (__bf16)x.x; bh[h][e0 + 1] = (__bf16)x.y;
            bh[h][e0 + 2] = (__bf16)x.z; bh[h][e0 + 3] = (__bf16)x.w;
            if (WRITE8) {
                int lo = __builtin_amdgcn_cvt_pk_fp8_f32(x.x, x.y, 0, false);
                pk[v]  = __builtin_amdgcn_cvt_pk_fp8_f32(x.z, x.w, lo, true);
            }
        }
        if (WRITE8) {
            uint4 u = {(unsigned)pk[0], (unsigned)pk[1], (unsigned)pk[2], (unsigned)pk[3]};
            *(uint4*)(j8row + k0 + gS * 16) = u;
        }
#pragma unroll
        for (int h = 0; h < 2; ++h) {
            const int off = cS * TW + ((gS * 16 + h * 8) ^ swzS);
            *(bf16x8*)&AhL[p][off] = ah[h];
            *(bf16x8*)&BhL[p][off] = bh[h];
        }
        __syncthreads();  // buf[p] published; prior reads of buf[p] were 2 barriers ago

#pragma unroll
        for (int s = 0; s < 4; ++s) {
            const int ks = khalf * 4 + s;
            const int kc = ks * 16 + kg * 8;
            bf16x8 a  = *(const bf16x8*)&AhL[p][abase + (kc ^ aswz)];
            bf16x8 bb = *(const bf16x8*)&BhL[p][bbase + (kc ^ bswz)];
            acc = __builtin_amdgcn_mfma_f32_32x32x16_bf16(a, bb, acc, 0, 0, 0);
        }
        // no second barrier: next tile writes the other buffer
    }

    __syncthreads();  // tile reads done -> overlay region safe to reuse

    // cross-wave k-half reduction: waves 4-7 stash, waves 0-3 add + write.
    if (khalf == 1) {
#pragma unroll
        for (int z = 0; z < 16; ++z) accred[qd][lane][z] = acc[z];
    }
    c0red[gS][cS] = c0acc;
    __syncthreads();

    if (khalf == 0) {
        // C/D layout (m74/m101): col = lane&31, row = (reg&3)+8*(reg>>2)+4*(lane>>5)
        float* Gp = Gpart + (size_t)(b * QB + qb) * 4096;
#pragma unroll
        for (int reg = 0; reg < 16; ++reg) {
            const int row = (reg & 3) + 8 * (reg >> 2) + 4 * kg;
            Gp[(i0 + row) * 64 + (j0 + r)] = acc[reg] + accred[qd][lane][reg];
        }
    }
    if (tid < 64) {
        float s = 0.0f;
#pragma unroll
        for (int g = 0; g < 8; ++g) s += c0red[g][tid];
        c0part[(b * QB + qb) * 64 + tid] = s;
    }
}

// ---------------- K2: Jacobi-Richardson solve  G z = c0, lmd = z/dtm ------
// One block (256 thr = 4 waves) per replica. G = sum of partials (SPD,
// diag-dominant: iteration matrix I - D^-1 G has spectral radius ~0.16,
// so 6 iterations leave ~4e-6 relative error, far below bf16-Gram noise).
// One barrier/iter: parity-buffered partials + wave-private z copy.
__global__ __launch_bounds__(256) void k2_solve(const float* __restrict__ Gpart,
                                                const float* __restrict__ c0part,
                                                const float* __restrict__ dtm,
                                                float* __restrict__ lmd_out) {
    __shared__ __align__(16) float G[64][68];
    __shared__ float red[2][4][64];
    __shared__ float zw[4][64];

    const int b = blockIdx.x;
    const int t = threadIdx.x;
    const int i = t & 63, q = t >> 6;

    // reduce the QB Gram partials (float4, coalesced)
    for (int e4 = t * 4; e4 < 4096; e4 += 1024) {
        float4 s = {0.0f, 0.0f, 0.0f, 0.0f};
#pragma unroll
        for (int qq = 0; qq < QB; ++qq) {
            float4 v = *(const float4*)&Gpart[(size_t)(b * QB + qq) * 4096 + e4];
            s.x += v.x; s.y += v.y; s.z += v.z; s.w += v.w;
        }
        *(float4*)&G[e4 >> 6][e4 & 63] = s;
    }
    // c0[i]: every thread (q,i) computes it (waves redundant, identical fp)
    float c0 = 0.0f;
#pragma unroll
    for (int qq = 0; qq < QB; ++qq) c0 += c0part[(b * QB + qq) * 64 + i];
    __syncthreads();  // G ready

    const float invD = 1.0f / G[i][i];
    float z = c0 * invD;          // z0 = D^-1 c0
    zw[q][i] = z;                 // wave-private copy (same-wave read only)

    for (int it = 0; it < 6; ++it) {
        float s = 0.0f;
        const float* gr = &G[i][q * 16];
        const float* zr = &zw[q][q * 16];
#pragma unroll
        for (int g = 0; g < 4; ++g) {
            float4 g4 = *(const float4*)&gr[4 * g];
            float4 z4 = *(const float4*)&zr[4 * g];   // broadcast (same addr/wave)
            s += g4.x * z4.x + g4.y * z4.y + g4.z * z4.z + g4.w * z4.w;
        }
        const int p = it & 1;
        red[p][q][i] = s;
        __syncthreads();  // red[p] complete
        const float rres = c0 - (red[p][0][i] + red[p][1][i] + red[p][2][i] + red[p][3][i]);
        z += rres * invD;         // identical in all 4 waves
        zw[q][i] = z;             // refresh own wave's copy (in-order DS)
    }

    if (t < 64) lmd_out[b * 64 + t] = z * (1.0f / dtm[b]);
}

// ---------------- K3 (fp8): mom_out = mom - dtm * jac8^T lmd --------------
// grid (6, 64), 256 thr. Each thread: 8 k-values; 64 rows x 8B fp8 loads
// (the 50 MB fp8 buffer was written by K1 just before -> L3-resident).
__global__ __launch_bounds__(256) void k3_momout_fp8(const unsigned char* __restrict__ jac8,
                                                     const float* __restrict__ mom,
                                                     const float* __restrict__ dtm,
                                                     const float* __restrict__ lmd,
                                                     float* __restrict__ mom_out) {
    __shared__ float lLds[64];
    const int b   = blockIdx.y;
    const int blk = blockIdx.x;
    const int t   = threadIdx.x;
    if (t < 64) lLds[t] = lmd[b * 64 + t];
    __syncthreads();

    const int kbase = blk * 2048 + t * 8;
    const unsigned char* jp = jac8 + (size_t)b * Cc * Kk + kbase;

    float acc[8];
#pragma unroll
    for (int z = 0; z < 8; ++z) acc[z] = 0.0f;

#pragma unroll 4
    for (int c = 0; c < 64; ++c) {
        uint2 u = *(const uint2*)(jp + (size_t)c * Kk);
        const float lc = lLds[c];
        f32x2 d;
        d = __builtin_amdgcn_cvt_pk_f32_fp8(u.x, false); acc[0] += lc * d[0]; acc[1] += lc * d[1];
        d = __builtin_amdgcn_cvt_pk_f32_fp8(u.x, true);  acc[2] += lc * d[0]; acc[3] += lc * d[1];
        d = __builtin_amdgcn_cvt_pk_f32_fp8(u.y, false); acc[4] += lc * d[0]; acc[5] += lc * d[1];
        d = __builtin_amdgcn_cvt_pk_f32_fp8(u.y, true);  acc[6] += lc * d[0]; acc[7] += lc * d[1];
    }
    const float dt = dtm[b];
    const float* mb = mom + (size_t)b * Kk + kbase;
    float4 m0 = *(const float4*)mb;
    float4 m1 = *(const float4*)(mb + 4);
    float4 o0, o1;
    o0.x = m0.x - dt * acc[0]; o0.y = m0.y - dt * acc[1];
    o0.z = m0.z - dt * acc[2]; o0.w = m0.w - dt * acc[3];
    o1.x = m1.x - dt * acc[4]; o1.y = m1.y - dt * acc[5];
    o1.z = m1.z - dt * acc[6]; o1.w = m1.w - dt * acc[7];
    float* ob = mom_out + (size_t)b * Kk + kbase;
    *(float4*)ob = o0;
    *(float4*)(ob + 4) = o1;
}

// ---------------- K3 (fp32 fallback, ws too small) ------------------------
__global__ __launch_bounds__(256) void k3_momout(const float* __restrict__ jac,
                                                 const float* __restrict__ mom,
                                                 const float* __restrict__ dtm,
                                                 const float* __restrict__ lmd,
                                                 float* __restrict__ mom_out) {
    __shared__ float lLds[64];
    const int b   = blockIdx.y;
    const int blk = blockIdx.x;
    const int t   = threadIdx.x;
    if (t < 64) lLds[t] = lmd[b * 64 + t];
    __syncthreads();

    const size_t kbase = (size_t)blk * 1024 + (size_t)t * 4;
    const float* jp = jac + (size_t)b * Cc * Kk + kbase;

    float4 acc = {0.0f, 0.0f, 0.0f, 0.0f};
#pragma unroll 4
    for (int c = 0; c < 64; ++c) {
        float4 jv = *(const float4*)(jp + (size_t)c * Kk);
        float lc = lLds[c];
        acc.x += lc * jv.x;
        acc.y += lc * jv.y;
        acc.z += lc * jv.z;
        acc.w += lc * jv.w;
    }
    const float dt = dtm[b];
    float4 m4 = *(const float4*)(mom + (size_t)b * Kk + kbase);
    float4 o;
    o.x = m4.x - dt * acc.x;
    o.y = m4.y - dt * acc.y;
    o.z = m4.z - dt * acc.z;
    o.w = m4.w - dt * acc.w;
    *(float4*)(mom_out + (size_t)b * Kk + kbase) = o;
}

extern "C" void kernel_launch(void* const* d_in, const int* in_sizes, int n_in,
                              void* d_out, int out_size, void* d_ws, size_t ws_size,
                              hipStream_t stream) {
    const float* mom = (const float*)d_in[0];
    const float* mas = (const float*)d_in[1];
    const float* dtm = (const float*)d_in[2];
    const float* jac = (const float*)d_in[3];

    float* out = (float*)d_out;            // mom_out: Bb*Kk
    float* lmd = out + (size_t)Bb * Kk;    // lmd: Bb*Cc

    const bool use_fp8 = ws_size >= WS_NEED;

    unsigned char* jac8 = (unsigned char*)d_ws;          // Bb*Cc*Kk bytes
    float* Gpart;
    float* c0part;
    if (use_fp8) {
        Gpart = (float*)(jac8 + J8_BYTES);
        c0part = Gpart + GPART_FLOATS;
    } else {
        Gpart = (float*)d_ws;
        c0part = Gpart + GPART_FLOATS;
    }

    if (use_fp8) {
        k1_gram<true><<<Bb * QB, 512, 0, stream>>>(jac, mas, mom, Gpart, c0part, jac8);
        k2_solve<<<Bb, 256, 0, stream>>>(Gpart, c0part, dtm, lmd);
        k3_momout_fp8<<<dim3(6, 64), 256, 0, stream>>>(jac8, mom, dtm, lmd, out);
    } else {
        k1_gram<false><<<Bb * QB, 512, 0, stream>>>(jac, mas, mom, Gpart, c0part, nullptr);
        k2_solve<<<Bb, 256, 0, stream>>>(Gpart, c0part, dtm, lmd);
        k3_momout<<<dim3(12, 64), 256, 0, stream>>>(jac, mom, dtm, lmd, out);
    }
}

// Round 10
// 61.845 us; speedup vs baseline: 1.7112x; 1.0183x over previous
//
#include <hip/hip_runtime.h>

// Rattle B=64, C=64, N=4096 (K = 12288). out = [mom_out (B*N*3), lmd (B*C)] fp32.
//
// G = (W.jac) jac^T = (S.jac)(S.jac)^T with S = diag(1/sqrt(mas))  (SPD)
// c0 = (W.jac).mom = (S.jac).(S.mom);  lmd = G^{-1} c0 / dtm
// mom_out = mom - dtm * jac^T lmd
//
// K1: SYMMETRIC bf16-MFMA Gram: stage ONE tile bf16(s*jac) (A and B
//     fragments read different rows of the same tile) -> ds_writes and
//     converts halve, LDS 70->38 KB (occupancy headroom). fp32 c0 path.
//     fp8-e4m3 jac copy for K3. 512 thr, QB=8, 128-wide dbuf k-tiles,
//     one barrier per tile (R8/R9 proven).
// K2: Jacobi-Richardson solve (rho ~0.16 -> 6 iters; 1 barrier/iter)
// K3: rank-64 momentum update reading the 50 MB fp8 copy (L3-resident)

namespace {
constexpr int Bb = 64;
constexpr int Cc = 64;
constexpr int Kk = 12288;
constexpr int QB = 8;             // K-chunks per replica
constexpr int KCHUNK = Kk / QB;   // 1536
constexpr int TW = 128;           // k-tile width
constexpr int NT = KCHUNK / TW;   // 12 tiles
constexpr size_t J8_BYTES = (size_t)Bb * Cc * Kk;          // 50,331,648
constexpr size_t GPART_FLOATS = (size_t)Bb * QB * 4096;    // 2,097,152
constexpr size_t C0_FLOATS = (size_t)Bb * QB * 64;         // 32,768
constexpr size_t WS_NEED = J8_BYTES + (GPART_FLOATS + C0_FLOATS) * 4;
}

typedef __attribute__((ext_vector_type(8))) __bf16 bf16x8;
typedef __attribute__((ext_vector_type(16))) float f32x16;
typedef __attribute__((ext_vector_type(2))) float f32x2;

// ---------------- K1: symmetric partial Gram via MFMA + fp32 c0 -----------
// grid 512 = (b, qb); 512 threads (8 waves). Each block: 64x64 Gram partial
// over a 1536-wide K chunk. ONE LDS bf16 tile [64 rows][128 k] (dbuf),
// XOR-swizzled (elem ^= (row&7)<<3): conflict-free 32-row b128 reads.
// Wave w: quadrant (w&3), k-half (w>>2); k-half pairs LDS-reduce at end.
template <bool WRITE8>
__global__ __launch_bounds__(512) void k1_gram(const float* __restrict__ jac,
                                               const float* __restrict__ mas,
                                               const float* __restrict__ mom,
                                               float* __restrict__ Gpart,
                                               float* __restrict__ c0part,
                                               unsigned char* __restrict__ jac8) {
    __shared__ __align__(16) __bf16 ShL[2][64 * TW];   // bf16(s * jac), dbuf (32 KB)
    __shared__ __align__(16) float sLds[KCHUNK];       // s = rsqrt(mas), 6 KB

    // epilogue-only scratch, overlaid on the dead tile buffers
    float (*accred)[64][17] = reinterpret_cast<float (*)[64][17]>(&ShL[0][0]);  // 17408 B
    float (*c0red)[64] = reinterpret_cast<float (*)[64]>(
        reinterpret_cast<char*>(&ShL[0][0]) + 4 * 64 * 17 * 4);                 // +2048 B

    const int b   = blockIdx.x >> 3;
    const int qb  = blockIdx.x & 7;
    const int tid = threadIdx.x;
    const int kbeg = qb * KCHUNK;

    // per-chunk weights s = 1/sqrt(mas) (fp32)
    for (int kk = tid; kk < KCHUNK; kk += 512)
        sLds[kk] = rsqrtf(mas[b * 4096 + (kbeg + kk) / 3]);

    // staging map: row cS (0..63), 16-float segment gS (0..7)
    const int cS = tid >> 3, gS = tid & 7;
    const float* jrow = jac + (size_t)(b * 64 + cS) * Kk;
    const float* momB = mom + (size_t)b * Kk;
    unsigned char* j8row = jac8 + (size_t)(b * 64 + cS) * Kk;  // byte/elem
    const int swzS = (cS & 7) << 3;

    // MFMA map: wave w -> quadrant qd=(w&3) -> (i0,j0); khalf=(w>>2) k-split
    const int w = tid >> 6, lane = tid & 63;
    const int qd = w & 3, khalf = w >> 2;
    const int i0 = (qd & 1) << 5, j0 = (qd >> 1) << 5;
    const int r = lane & 31, kg = lane >> 5;
    const int arow = i0 + r, brow = j0 + r;
    const int abase = arow * TW, aswz = (arow & 7) << 3;
    const int bbase = brow * TW, bswz = (brow & 7) << 3;

    f32x16 acc;
#pragma unroll
    for (int z = 0; z < 16; ++z) acc[z] = 0.0f;
    float c0acc = 0.0f;

    __syncthreads();  // sLds ready

    for (int t = 0; t < NT; ++t) {
        const int p = t & 1;
        const int k0 = kbeg + t * TW;
        const float4* jp = (const float4*)(jrow + k0 + gS * 16);
        const float4* sp = (const float4*)(sLds + (k0 - kbeg) + gS * 16);
        const float4* mp = (const float4*)(momB + k0 + gS * 16);

        bf16x8 sh[2];
        int pk[4];
#pragma unroll
        for (int v = 0; v < 4; ++v) {
            float4 x = jp[v];
            float4 sv = sp[v];
            float4 m = mp[v];
            float y0 = x.x * sv.x, y1 = x.y * sv.y, y2 = x.z * sv.z, y3 = x.w * sv.w;
            // c0 += (s x)(s m) = w x m   (fp32 exact path)
            c0acc += y0 * (sv.x * m.x) + y1 * (sv.y * m.y)
                   + y2 * (sv.z * m.z) + y3 * (sv.w * m.w);
            const int h = v >> 1, e0 = (v & 1) * 4;
            sh[h][e0 + 0] = (__bf16)y0; sh[h][e0 + 1] = (__bf16)y1;
            sh[h][e0 + 2] = (__bf16)y2; sh[h][e0 + 3] = (__bf16)y3;
            if (WRITE8) {
                int lo = __builtin_amdgcn_cvt_pk_fp8_f32(x.x, x.y, 0, false);
                pk[v]  = __builtin_amdgcn_cvt_pk_fp8_f32(x.z, x.w, lo, true);
            }
        }
        if (WRITE8) {
            uint4 u = {(unsigned)pk[0], (unsigned)pk[1], (unsigned)pk[2], (unsigned)pk[3]};
            *(uint4*)(j8row + k0 + gS * 16) = u;
        }
#pragma unroll
        for (int h = 0; h < 2; ++h) {
            const int off = cS * TW + ((gS * 16 + h * 8) ^ swzS);
            *(bf16x8*)&ShL[p][off] = sh[h];
        }
        __syncthreads();  // buf[p] published; prior reads were 2 barriers ago

#pragma unroll
        for (int s = 0; s < 4; ++s) {
            const int ks = khalf * 4 + s;
            const int kc = ks * 16 + kg * 8;
            bf16x8 a  = *(const bf16x8*)&ShL[p][abase + (kc ^ aswz)];
            bf16x8 bb = *(const bf16x8*)&ShL[p][bbase + (kc ^ bswz)];
            acc = __builtin_amdgcn_mfma_f32_32x32x16_bf16(a, bb, acc, 0, 0, 0);
        }
        // no second barrier: next tile writes the other buffer
    }

    __syncthreads();  // tile reads done -> overlay region safe to reuse

    // cross-wave k-half reduction: waves 4-7 stash, waves 0-3 add + write.
    if (khalf == 1) {
#pragma unroll
        for (int z = 0; z < 16; ++z) accred[qd][lane][z] = acc[z];
    }
    c0red[gS][cS] = c0acc;
    __syncthreads();

    if (khalf == 0) {
        // C/D layout (m74/m101): col = lane&31, row = (reg&3)+8*(reg>>2)+4*(lane>>5)
        float* Gp = Gpart + (size_t)(b * QB + qb) * 4096;
#pragma unroll
        for (int reg = 0; reg < 16; ++reg) {
            const int row = (reg & 3) + 8 * (reg >> 2) + 4 * kg;
            Gp[(i0 + row) * 64 + (j0 + r)] = acc[reg] + accred[qd][lane][reg];
        }
    }
    if (tid < 64) {
        float s = 0.0f;
#pragma unroll
        for (int g = 0; g < 8; ++g) s += c0red[g][tid];
        c0part[(b * QB + qb) * 64 + tid] = s;
    }
}

// ---------------- K2: Jacobi-Richardson solve  G z = c0, lmd = z/dtm ------
// One block (256 thr = 4 waves) per replica. G = sum of partials (SPD,
// diag-dominant: iteration matrix I - D^-1 G has spectral radius ~0.16,
// so 6 iterations leave ~4e-6 relative error, far below bf16-Gram noise).
// One barrier/iter: parity-buffered partials + wave-private z copy.
__global__ __launch_bounds__(256) void k2_solve(const float* __restrict__ Gpart,
                                                const float* __restrict__ c0part,
                                                const float* __restrict__ dtm,
                                                float* __restrict__ lmd_out) {
    __shared__ __align__(16) float G[64][68];
    __shared__ float red[2][4][64];
    __shared__ float zw[4][64];

    const int b = blockIdx.x;
    const int t = threadIdx.x;
    const int i = t & 63, q = t >> 6;

    // reduce the QB Gram partials (float4, coalesced)
    for (int e4 = t * 4; e4 < 4096; e4 += 1024) {
        float4 s = {0.0f, 0.0f, 0.0f, 0.0f};
#pragma unroll
        for (int qq = 0; qq < QB; ++qq) {
            float4 v = *(const float4*)&Gpart[(size_t)(b * QB + qq) * 4096 + e4];
            s.x += v.x; s.y += v.y; s.z += v.z; s.w += v.w;
        }
        *(float4*)&G[e4 >> 6][e4 & 63] = s;
    }
    // c0[i]: every thread (q,i) computes it (waves redundant, identical fp)
    float c0 = 0.0f;
#pragma unroll
    for (int qq = 0; qq < QB; ++qq) c0 += c0part[(b * QB + qq) * 64 + i];
    __syncthreads();  // G ready

    const float invD = 1.0f / G[i][i];
    float z = c0 * invD;          // z0 = D^-1 c0
    zw[q][i] = z;                 // wave-private copy (same-wave read only)

    for (int it = 0; it < 6; ++it) {
        float s = 0.0f;
        const float* gr = &G[i][q * 16];
        const float* zr = &zw[q][q * 16];
#pragma unroll
        for (int g = 0; g < 4; ++g) {
            float4 g4 = *(const float4*)&gr[4 * g];
            float4 z4 = *(const float4*)&zr[4 * g];   // broadcast (same addr/wave)
            s += g4.x * z4.x + g4.y * z4.y + g4.z * z4.z + g4.w * z4.w;
        }
        const int p = it & 1;
        red[p][q][i] = s;
        __syncthreads();  // red[p] complete
        const float rres = c0 - (red[p][0][i] + red[p][1][i] + red[p][2][i] + red[p][3][i]);
        z += rres * invD;         // identical in all 4 waves
        zw[q][i] = z;             // refresh own wave's copy (in-order DS)
    }

    if (t < 64) lmd_out[b * 64 + t] = z * (1.0f / dtm[b]);
}

// ---------------- K3 (fp8): mom_out = mom - dtm * jac8^T lmd --------------
// grid (6, 64), 256 thr. Each thread: 8 k-values; 64 rows x 8B fp8 loads
// (the 50 MB fp8 buffer was written by K1 just before -> L3-resident).
__global__ __launch_bounds__(256) void k3_momout_fp8(const unsigned char* __restrict__ jac8,
                                                     const float* __restrict__ mom,
                                                     const float* __restrict__ dtm,
                                                     const float* __restrict__ lmd,
                                                     float* __restrict__ mom_out) {
    __shared__ float lLds[64];
    const int b   = blockIdx.y;
    const int blk = blockIdx.x;
    const int t   = threadIdx.x;
    if (t < 64) lLds[t] = lmd[b * 64 + t];
    __syncthreads();

    const int kbase = blk * 2048 + t * 8;
    const unsigned char* jp = jac8 + (size_t)b * Cc * Kk + kbase;

    float acc[8];
#pragma unroll
    for (int z = 0; z < 8; ++z) acc[z] = 0.0f;

#pragma unroll 4
    for (int c = 0; c < 64; ++c) {
        uint2 u = *(const uint2*)(jp + (size_t)c * Kk);
        const float lc = lLds[c];
        f32x2 d;
        d = __builtin_amdgcn_cvt_pk_f32_fp8(u.x, false); acc[0] += lc * d[0]; acc[1] += lc * d[1];
        d = __builtin_amdgcn_cvt_pk_f32_fp8(u.x, true);  acc[2] += lc * d[0]; acc[3] += lc * d[1];
        d = __builtin_amdgcn_cvt_pk_f32_fp8(u.y, false); acc[4] += lc * d[0]; acc[5] += lc * d[1];
        d = __builtin_amdgcn_cvt_pk_f32_fp8(u.y, true);  acc[6] += lc * d[0]; acc[7] += lc * d[1];
    }
    const float dt = dtm[b];
    const float* mb = mom + (size_t)b * Kk + kbase;
    float4 m0 = *(const float4*)mb;
    float4 m1 = *(const float4*)(mb + 4);
    float4 o0, o1;
    o0.x = m0.x - dt * acc[0]; o0.y = m0.y - dt * acc[1];
    o0.z = m0.z - dt * acc[2]; o0.w = m0.w - dt * acc[3];
    o1.x = m1.x - dt * acc[4]; o1.y = m1.y - dt * acc[5];
    o1.z = m1.z - dt * acc[6]; o1.w = m1.w - dt * acc[7];
    float* ob = mom_out + (size_t)b * Kk + kbase;
    *(float4*)ob = o0;
    *(float4*)(ob + 4) = o1;
}

// ---------------- K3 (fp32 fallback, ws too small) ------------------------
__global__ __launch_bounds__(256) void k3_momout(const float* __restrict__ jac,
                                                 const float* __restrict__ mom,
                                                 const float* __restrict__ dtm,
                                                 const float* __restrict__ lmd,
                                                 float* __restrict__ mom_out) {
    __shared__ float lLds[64];
    const int b   = blockIdx.y;
    const int blk = blockIdx.x;
    const int t   = threadIdx.x;
    if (t < 64) lLds[t] = lmd[b * 64 + t];
    __syncthreads();

    const size_t kbase = (size_t)blk * 1024 + (size_t)t * 4;
    const float* jp = jac + (size_t)b * Cc * Kk + kbase;

    float4 acc = {0.0f, 0.0f, 0.0f, 0.0f};
#pragma unroll 4
    for (int c = 0; c < 64; ++c) {
        float4 jv = *(const float4*)(jp + (size_t)c * Kk);
        float lc = lLds[c];
        acc.x += lc * jv.x;
        acc.y += lc * jv.y;
        acc.z += lc * jv.z;
        acc.w += lc * jv.w;
    }
    const float dt = dtm[b];
    float4 m4 = *(const float4*)(mom + (size_t)b * Kk + kbase);
    float4 o;
    o.x = m4.x - dt * acc.x;
    o.y = m4.y - dt * acc.y;
    o.z = m4.z - dt * acc.z;
    o.w = m4.w - dt * acc.w;
    *(float4*)(mom_out + (size_t)b * Kk + kbase) = o;
}

extern "C" void kernel_launch(void* const* d_in, const int* in_sizes, int n_in,
                              void* d_out, int out_size, void* d_ws, size_t ws_size,
                              hipStream_t stream) {
    const float* mom = (const float*)d_in[0];
    const float* mas = (const float*)d_in[1];
    const float* dtm = (const float*)d_in[2];
    const float* jac = (const float*)d_in[3];

    float* out = (float*)d_out;            // mom_out: Bb*Kk
    float* lmd = out + (size_t)Bb * Kk;    // lmd: Bb*Cc

    const bool use_fp8 = ws_size >= WS_NEED;

    unsigned char* jac8 = (unsigned char*)d_ws;          // Bb*Cc*Kk bytes
    float* Gpart;
    float* c0part;
    if (use_fp8) {
        Gpart = (float*)(jac8 + J8_BYTES);
        c0part = Gpart + GPART_FLOATS;
    } else {
        Gpart = (float*)d_ws;
        c0part = Gpart + GPART_FLOATS;
    }

    if (use_fp8) {
        k1_gram<true><<<Bb * QB, 512, 0, stream>>>(jac, mas, mom, Gpart, c0part, jac8);
        k2_solve<<<Bb, 256, 0, stream>>>(Gpart, c0part, dtm, lmd);
        k3_momout_fp8<<<dim3(6, 64), 256, 0, stream>>>(jac8, mom, dtm, lmd, out);
    } else {
        k1_gram<false><<<Bb * QB, 512, 0, stream>>>(jac, mas, mom, Gpart, c0part, nullptr);
        k2_solve<<<Bb, 256, 0, stream>>>(Gpart, c0part, dtm, lmd);
        k3_momout<<<dim3(12, 64), 256, 0, stream>>>(jac, mom, dtm, lmd, out);
    }
}